// Round 1
// baseline (2430.969 us; speedup 1.0000x reference)
//
#include <hip/hip_runtime.h>
#include <hip/hip_bf16.h>
#include <math.h>

#define H_    16
#define KV_   8
#define D_    128
#define HID_  2048
#define SCALE_ 0.08838834764831845f   // 128^-0.5

// ---------------- fp32 tiled GEMM: C(M,N) = A(M,K) @ B(K,N) ----------------
#define GBM 64
#define GBN 64
#define GBK 32

__global__ __launch_bounds__(256) void gemm_f32(
    const float* __restrict__ A, const float* __restrict__ B,
    float* __restrict__ C, int M, int N, int K) {
  __shared__ float As[GBK][GBM + 4];   // transposed: As[k][m]; row = 272B (16B-aligned)
  __shared__ float Bs[GBK][GBN + 4];
  const int tid = threadIdx.x;
  const int tx = tid & 15, ty = tid >> 4;
  const int row0 = blockIdx.y * GBM, col0 = blockIdx.x * GBN;
  const int a_m = tid >> 3;          // 0..31 (two passes +32)
  const int a_k = (tid & 7) << 2;    // 0..28
  const int b_n = (tid & 15) << 2;   // 0..60
  const int b_k = tid >> 4;          // 0..15 (two passes +16)
  float acc[4][4] = {{0.f}};
  for (int k0 = 0; k0 < K; k0 += GBK) {
#pragma unroll
    for (int p = 0; p < 2; ++p) {
      int m = a_m + p * 32;
      float4 av = *(const float4*)(A + (size_t)(row0 + m) * K + k0 + a_k);
      As[a_k + 0][m] = av.x; As[a_k + 1][m] = av.y;
      As[a_k + 2][m] = av.z; As[a_k + 3][m] = av.w;
    }
#pragma unroll
    for (int p = 0; p < 2; ++p) {
      int kk = b_k + p * 16;
      *(float4*)(&Bs[kk][b_n]) = *(const float4*)(B + (size_t)(k0 + kk) * N + col0 + b_n);
    }
    __syncthreads();
#pragma unroll 8
    for (int kk = 0; kk < GBK; ++kk) {
      float4 a4 = *(const float4*)(&As[kk][ty << 2]);
      float4 b4 = *(const float4*)(&Bs[kk][tx << 2]);
      float av[4] = {a4.x, a4.y, a4.z, a4.w};
      float bv[4] = {b4.x, b4.y, b4.z, b4.w};
#pragma unroll
      for (int i = 0; i < 4; ++i)
#pragma unroll
        for (int j = 0; j < 4; ++j)
          acc[i][j] = fmaf(av[i], bv[j], acc[i][j]);
    }
    __syncthreads();
  }
#pragma unroll
  for (int i = 0; i < 4; ++i) {
    float4 o = {acc[i][0], acc[i][1], acc[i][2], acc[i][3]};
    *(float4*)(C + (size_t)(row0 + (ty << 2) + i) * N + col0 + (tx << 2)) = o;
  }
}

// ------------- fused per-head RMSNorm + RoPE (in place) -------------
// p: (rows, 128) where rows = B*S*nheads; cos/sin: (B*S, 128)
__global__ __launch_bounds__(256) void rmsnorm_rope(
    float* __restrict__ p, const float* __restrict__ w,
    const float* __restrict__ cs, const float* __restrict__ sn, int nheads) {
  const int row  = blockIdx.x * 4 + (threadIdx.x >> 6);
  const int lane = threadIdx.x & 63;
  float* base = p + (size_t)row * D_;
  float x1 = base[lane];
  float x2 = base[lane + 64];
  float ss = x1 * x1 + x2 * x2;
#pragma unroll
  for (int m = 32; m; m >>= 1) ss += __shfl_xor(ss, m);
  float r = rsqrtf(ss * (1.0f / 128.0f) + 1e-6f);
  const size_t sidx = (size_t)(row / nheads) * D_;
  float n1 = x1 * r * w[lane];
  float n2 = x2 * r * w[lane + 64];
  // rotate_half: d<64 -> -x[d+64]; d>=64 -> x[d-64]
  base[lane]      = n1 * cs[sidx + lane]      - n2 * sn[sidx + lane];
  base[lane + 64] = n2 * cs[sidx + lane + 64] + n1 * sn[sidx + lane + 64];
}

// ------------- fp32 causal flash attention, GQA -------------
// Q: (B*S, H*D) [pre-scaled by SCALE_ at staging], K/V: (B*S, KV*D), O: (B*S, H*D)
__global__ __launch_bounds__(256) void flash_f32(
    const float* __restrict__ Q, const float* __restrict__ Kb,
    const float* __restrict__ Vb, float* __restrict__ O,
    int S, int groups) {
  __shared__ float Qs[128 * 64];   // [d][r]
  __shared__ float KVs[128 * 64];  // K phase: [d][c] (128x64); V phase: [c][dv] (64x128)
  __shared__ float Pt[64 * 64];    // [c][r]
  const int qt = blockIdx.x, h = blockIdx.y, b = blockIdx.z;
  const int kvh = h / groups;
  const int tid = threadIdx.x;
  const int tx = tid & 15, ty = tid >> 4;
  const int r0 = ty << 2, c0 = tx << 2;
  const int q0 = qt * 64;
  const size_t qstr = (size_t)H_ * D_;    // 2048
  const size_t kstr = (size_t)KV_ * D_;   // 1024
  const float* Qp = Q  + (size_t)b * S * qstr + (size_t)h   * D_;
  const float* Kp = Kb + (size_t)b * S * kstr + (size_t)kvh * D_;
  const float* Vp = Vb + (size_t)b * S * kstr + (size_t)kvh * D_;

  {  // stage Q transposed + scaled
    const int r = tid >> 2, d0 = (tid & 3) << 2;
    const float* src = Qp + (size_t)(q0 + r) * qstr;
#pragma unroll
    for (int p = 0; p < 8; ++p) {
      int d = d0 + p * 16;
      float4 v = *(const float4*)(src + d);
      Qs[(d + 0) * 64 + r] = v.x * SCALE_;
      Qs[(d + 1) * 64 + r] = v.y * SCALE_;
      Qs[(d + 2) * 64 + r] = v.z * SCALE_;
      Qs[(d + 3) * 64 + r] = v.w * SCALE_;
    }
  }

  float acc[4][8] = {{0.f}};
  float mrow[4] = {-1e30f, -1e30f, -1e30f, -1e30f};
  float lrow[4] = {0.f, 0.f, 0.f, 0.f};
  const int nt = qt + 1;

  for (int kt = 0; kt < nt; ++kt) {
    __syncthreads();  // prev V/Pt reads done; (iter 0: Q staged)
    {  // stage K transposed: KVs[d][c]
      const int c = tid >> 2, d0 = (tid & 3) << 2;
      const float* src = Kp + (size_t)(kt * 64 + c) * kstr;
#pragma unroll
      for (int p = 0; p < 8; ++p) {
        int d = d0 + p * 16;
        float4 v = *(const float4*)(src + d);
        KVs[(d + 0) * 64 + c] = v.x;
        KVs[(d + 1) * 64 + c] = v.y;
        KVs[(d + 2) * 64 + c] = v.z;
        KVs[(d + 3) * 64 + c] = v.w;
      }
    }
    __syncthreads();

    float s[4][4] = {{0.f}};
#pragma unroll 8
    for (int d = 0; d < 128; ++d) {
      float4 qa = *(const float4*)(&Qs[d * 64 + r0]);
      float4 ka = *(const float4*)(&KVs[d * 64 + c0]);
      float qv[4] = {qa.x, qa.y, qa.z, qa.w};
      float kv[4] = {ka.x, ka.y, ka.z, ka.w};
#pragma unroll
      for (int i = 0; i < 4; ++i)
#pragma unroll
        for (int j = 0; j < 4; ++j)
          s[i][j] = fmaf(qv[i], kv[j], s[i][j]);
    }

    if (kt == qt) {  // diagonal tile: causal mask (same tile offset => compare locals)
#pragma unroll
      for (int i = 0; i < 4; ++i)
#pragma unroll
        for (int j = 0; j < 4; ++j)
          if (c0 + j > r0 + i) s[i][j] = -1e30f;
    }

    float al[4];
#pragma unroll
    for (int i = 0; i < 4; ++i) {
      float m = fmaxf(fmaxf(s[i][0], s[i][1]), fmaxf(s[i][2], s[i][3]));
      m = fmaxf(m, __shfl_xor(m, 1));
      m = fmaxf(m, __shfl_xor(m, 2));
      m = fmaxf(m, __shfl_xor(m, 4));
      m = fmaxf(m, __shfl_xor(m, 8));
      float mn = fmaxf(mrow[i], m);
      al[i] = __expf(mrow[i] - mn);
      mrow[i] = mn;
      float rsum = 0.f;
#pragma unroll
      for (int j = 0; j < 4; ++j) { s[i][j] = __expf(s[i][j] - mn); rsum += s[i][j]; }
      rsum += __shfl_xor(rsum, 1);
      rsum += __shfl_xor(rsum, 2);
      rsum += __shfl_xor(rsum, 4);
      rsum += __shfl_xor(rsum, 8);
      lrow[i] = lrow[i] * al[i] + rsum;
#pragma unroll
      for (int j = 0; j < 8; ++j) acc[i][j] *= al[i];
    }
    __syncthreads();  // all K reads done -> safe to overwrite KVs with V; Pt free

#pragma unroll
    for (int j = 0; j < 4; ++j) {  // P transposed: Pt[c][r]
      float4 w4 = {s[0][j], s[1][j], s[2][j], s[3][j]};
      *(float4*)(&Pt[(c0 + j) * 64 + r0]) = w4;
    }
    {  // stage V row-major: KVs[c][dv]
      const int dv = (tid & 31) << 2, cl = tid >> 5;
#pragma unroll
      for (int p = 0; p < 8; ++p) {
        int c = cl + p * 8;
        *(float4*)(&KVs[c * 128 + dv]) =
            *(const float4*)(Vp + (size_t)(kt * 64 + c) * kstr + dv);
      }
    }
    __syncthreads();

#pragma unroll 4
    for (int c = 0; c < 64; ++c) {  // O += P @ V
      float4 pv  = *(const float4*)(&Pt[c * 64 + r0]);
      float4 va  = *(const float4*)(&KVs[c * 128 + c0]);
      float4 vb2 = *(const float4*)(&KVs[c * 128 + 64 + c0]);
      float pr[4] = {pv.x, pv.y, pv.z, pv.w};
      float va_[4] = {va.x, va.y, va.z, va.w};
      float vb_[4] = {vb2.x, vb2.y, vb2.z, vb2.w};
#pragma unroll
      for (int i = 0; i < 4; ++i) {
#pragma unroll
        for (int j = 0; j < 4; ++j) {
          acc[i][j]     = fmaf(pr[i], va_[j], acc[i][j]);
          acc[i][j + 4] = fmaf(pr[i], vb_[j], acc[i][j + 4]);
        }
      }
    }
  }

#pragma unroll
  for (int i = 0; i < 4; ++i) {
    float inv = 1.0f / lrow[i];
    const size_t orow = (size_t)(b * S + q0 + r0 + i) * qstr + (size_t)h * D_;
    float4 o1 = {acc[i][0] * inv, acc[i][1] * inv, acc[i][2] * inv, acc[i][3] * inv};
    float4 o2 = {acc[i][4] * inv, acc[i][5] * inv, acc[i][6] * inv, acc[i][7] * inv};
    *(float4*)(O + orow + c0) = o1;
    *(float4*)(O + orow + 64 + c0) = o2;
  }
}

extern "C" void kernel_launch(void* const* d_in, const int* in_sizes, int n_in,
                              void* d_out, int out_size, void* d_ws, size_t ws_size,
                              hipStream_t stream) {
  const float* x  = (const float*)d_in[0];
  const float* sn = (const float*)d_in[1];   // sin
  const float* cs = (const float*)d_in[2];   // cos
  // d_in[3] = attention_mask: causal, applied analytically -> unused
  const float* Wq = (const float*)d_in[4];
  const float* Wk = (const float*)d_in[5];
  const float* Wv = (const float*)d_in[6];
  const float* Wo = (const float*)d_in[7];
  const float* qw = (const float*)d_in[8];
  const float* kw = (const float*)d_in[9];
  float* out = (float*)d_out;
  float* ws  = (float*)d_ws;

  const int BS = in_sizes[0] / HID_;   // B*S
  const int S  = in_sizes[3] / BS;     // mask has B*S*S elements
  const int B  = BS / S;

  float* kbuf = ws;                                  // BS * KV * D
  float* vbuf = kbuf + (size_t)BS * KV_ * D_;        // BS * KV * D
  float* abuf = vbuf + (size_t)BS * KV_ * D_;        // BS * H  * D

  dim3 blk(256);
  // QKV projections (q lives in d_out until the final GEMM overwrites it)
  gemm_f32<<<dim3((H_ * D_) / GBN, BS / GBM), blk, 0, stream>>>(x, Wq, out,  BS, H_ * D_,  HID_);
  gemm_f32<<<dim3((KV_ * D_) / GBN, BS / GBM), blk, 0, stream>>>(x, Wk, kbuf, BS, KV_ * D_, HID_);
  gemm_f32<<<dim3((KV_ * D_) / GBN, BS / GBM), blk, 0, stream>>>(x, Wv, vbuf, BS, KV_ * D_, HID_);
  // per-head RMSNorm + RoPE (in place)
  rmsnorm_rope<<<dim3(BS * H_ / 4),  blk, 0, stream>>>(out,  qw, cs, sn, H_);
  rmsnorm_rope<<<dim3(BS * KV_ / 4), blk, 0, stream>>>(kbuf, kw, cs, sn, KV_);
  // causal flash attention (GQA groups = H/KV)
  flash_f32<<<dim3(S / 64, H_, B), blk, 0, stream>>>(out, kbuf, vbuf, abuf, S, H_ / KV_);
  // output projection
  gemm_f32<<<dim3(HID_ / GBN, BS / GBM), blk, 0, stream>>>(abuf, Wo, out, BS, HID_, HID_);
}

// Round 2
// 1234.047 us; speedup vs baseline: 1.9699x; 1.9699x over previous
//
#include <hip/hip_runtime.h>
#include <hip/hip_bf16.h>
#include <math.h>

#define H_    16
#define KV_   8
#define D_    128
#define HID_  2048
#define SCALE_ 0.08838834764831845f   // 128^-0.5

typedef __attribute__((ext_vector_type(8))) short bf16x8;
typedef __attribute__((ext_vector_type(4))) float f32x4;
typedef __attribute__((ext_vector_type(4))) short short4v;

__device__ inline unsigned short f2bf(float f) {
  unsigned u = __builtin_bit_cast(unsigned, f);
  u += 0x7FFF + ((u >> 16) & 1);   // RNE
  return (unsigned short)(u >> 16);
}

#define GLDS16(g, l)                                                     \
  __builtin_amdgcn_global_load_lds(                                      \
      (const __attribute__((address_space(1))) void*)(g),                \
      (__attribute__((address_space(3))) void*)(l), 16, 0, 0)

// ---------------- f32 -> bf16 (contiguous, x8 per thread) ----------------
__global__ __launch_bounds__(256) void f32_to_bf16(
    const float* __restrict__ in, unsigned short* __restrict__ out, int n8) {
  int i = blockIdx.x * 256 + threadIdx.x;
  if (i >= n8) return;
  const float4* p = (const float4*)in + (size_t)i * 2;
  float4 a = p[0], b = p[1];
  unsigned short o[8] = {f2bf(a.x), f2bf(a.y), f2bf(a.z), f2bf(a.w),
                         f2bf(b.x), f2bf(b.y), f2bf(b.z), f2bf(b.w)};
  *(bf16x8*)(out + (size_t)i * 8) = *(bf16x8*)o;
}

// ------------- f32 (K x N) -> bf16 transposed (N x K) -------------
__global__ __launch_bounds__(256) void transpose_bf16(
    const float* __restrict__ in, unsigned short* __restrict__ out, int K, int N) {
  __shared__ float t[32][33];
  const int k0 = blockIdx.y * 32, n0 = blockIdx.x * 32;
  const int r = threadIdx.x >> 3, c4 = (threadIdx.x & 7) * 4;
  float4 v = *(const float4*)(in + (size_t)(k0 + r) * N + n0 + c4);
  t[r][c4 + 0] = v.x; t[r][c4 + 1] = v.y; t[r][c4 + 2] = v.z; t[r][c4 + 3] = v.w;
  __syncthreads();
  unsigned short o[4];
#pragma unroll
  for (int j = 0; j < 4; ++j) o[j] = f2bf(t[c4 + j][r]);
  *(short4v*)(out + (size_t)(n0 + r) * K + k0 + c4) = *(short4v*)o;
}

// ---------------- bf16 MFMA GEMM: C(M,N) = A(M,K) @ Bt(N,K)^T ----------------
// m97 structure: 128x128 tile, BK=64, 4 waves (2x2), global_load_lds staging.
#define TBM 128
#define TBN 128
#define TBK 64

__global__ __launch_bounds__(256) void gemm_bf16(
    const unsigned short* __restrict__ A,   // M x K row-major
    const unsigned short* __restrict__ Bt,  // N x K row-major
    float* __restrict__ C, int M, int N, int K) {
  __shared__ unsigned short As[TBM * TBK];  // [m][k], 16 KB
  __shared__ unsigned short Bs[TBN * TBK];  // [n][k], 16 KB
  const int tid = threadIdx.x;
  const int w = tid >> 6, lane = tid & 63;
  const int wm = w >> 1, wn = w & 1;
  const int fr = lane & 15, fq = lane >> 4;
  const int row0 = blockIdx.y * TBM, col0 = blockIdx.x * TBN;

  const unsigned short* Ab = A + (size_t)row0 * K;
  const unsigned short* Bb = Bt + (size_t)col0 * K;
  const int sm = lane >> 3;         // row within 8-row segment
  const int sk = (lane & 7) * 8;    // k offset (8 elems = 16B)

  f32x4 acc[4][4] = {};

  for (int k0 = 0; k0 < K; k0 += TBK) {
    __syncthreads();   // previous tile's LDS reads drained
#pragma unroll
    for (int p = 0; p < 4; ++p) {
      const int seg = w * 4 + p;            // 0..15, wave-uniform
      const int m = seg * 8 + sm;
      GLDS16(Ab + (size_t)m * K + k0 + sk, As + seg * 512);
      GLDS16(Bb + (size_t)m * K + k0 + sk, Bs + seg * 512);
    }
    __syncthreads();   // compiler drains vmcnt(0) before barrier -> tile ready
#pragma unroll
    for (int s = 0; s < 2; ++s) {
      bf16x8 af[4], bfr[4];
#pragma unroll
      for (int i = 0; i < 4; ++i)
        af[i] = *(const bf16x8*)(As + (wm * 64 + i * 16 + fr) * TBK + s * 32 + fq * 8);
#pragma unroll
      for (int j = 0; j < 4; ++j)
        bfr[j] = *(const bf16x8*)(Bs + (wn * 64 + j * 16 + fr) * TBK + s * 32 + fq * 8);
#pragma unroll
      for (int i = 0; i < 4; ++i)
#pragma unroll
        for (int j = 0; j < 4; ++j)
          acc[i][j] = __builtin_amdgcn_mfma_f32_16x16x32_bf16(af[i], bfr[j], acc[i][j], 0, 0, 0);
    }
  }

  // C/D layout (m89-verified): col = lane&15, row = (lane>>4)*4 + reg
#pragma unroll
  for (int i = 0; i < 4; ++i)
#pragma unroll
    for (int j = 0; j < 4; ++j) {
      const int col = col0 + wn * 64 + j * 16 + fr;
#pragma unroll
      for (int r = 0; r < 4; ++r) {
        const int row = row0 + wm * 64 + i * 16 + fq * 4 + r;
        C[(size_t)row * N + col] = acc[i][j][r];
      }
    }
}

// ------------- fused per-head RMSNorm + RoPE (in place, fp32) -------------
__global__ __launch_bounds__(256) void rmsnorm_rope(
    float* __restrict__ p, const float* __restrict__ w,
    const float* __restrict__ cs, const float* __restrict__ sn, int nheads) {
  const int row  = blockIdx.x * 4 + (threadIdx.x >> 6);
  const int lane = threadIdx.x & 63;
  float* base = p + (size_t)row * D_;
  float x1 = base[lane];
  float x2 = base[lane + 64];
  float ss = x1 * x1 + x2 * x2;
#pragma unroll
  for (int m = 32; m; m >>= 1) ss += __shfl_xor(ss, m);
  float r = rsqrtf(ss * (1.0f / 128.0f) + 1e-6f);
  const size_t sidx = (size_t)(row / nheads) * D_;
  float n1 = x1 * r * w[lane];
  float n2 = x2 * r * w[lane + 64];
  base[lane]      = n1 * cs[sidx + lane]      - n2 * sn[sidx + lane];
  base[lane + 64] = n2 * cs[sidx + lane + 64] + n1 * sn[sidx + lane + 64];
}

// ------------- fp32 causal flash attention, GQA (unchanged) -------------
__global__ __launch_bounds__(256) void flash_f32(
    const float* __restrict__ Q, const float* __restrict__ Kb,
    const float* __restrict__ Vb, float* __restrict__ O,
    int S, int groups) {
  __shared__ float Qs[128 * 64];   // [d][r]
  __shared__ float KVs[128 * 64];  // K phase: [d][c]; V phase: [c][dv]
  __shared__ float Pt[64 * 64];    // [c][r]
  const int qt = blockIdx.x, h = blockIdx.y, b = blockIdx.z;
  const int kvh = h / groups;
  const int tid = threadIdx.x;
  const int tx = tid & 15, ty = tid >> 4;
  const int r0 = ty << 2, c0 = tx << 2;
  const int q0 = qt * 64;
  const size_t qstr = (size_t)H_ * D_;
  const size_t kstr = (size_t)KV_ * D_;
  const float* Qp = Q  + (size_t)b * S * qstr + (size_t)h   * D_;
  const float* Kp = Kb + (size_t)b * S * kstr + (size_t)kvh * D_;
  const float* Vp = Vb + (size_t)b * S * kstr + (size_t)kvh * D_;

  {  // stage Q transposed + scaled
    const int r = tid >> 2, d0 = (tid & 3) << 2;
    const float* src = Qp + (size_t)(q0 + r) * qstr;
#pragma unroll
    for (int p = 0; p < 8; ++p) {
      int d = d0 + p * 16;
      float4 v = *(const float4*)(src + d);
      Qs[(d + 0) * 64 + r] = v.x * SCALE_;
      Qs[(d + 1) * 64 + r] = v.y * SCALE_;
      Qs[(d + 2) * 64 + r] = v.z * SCALE_;
      Qs[(d + 3) * 64 + r] = v.w * SCALE_;
    }
  }

  float acc[4][8] = {{0.f}};
  float mrow[4] = {-1e30f, -1e30f, -1e30f, -1e30f};
  float lrow[4] = {0.f, 0.f, 0.f, 0.f};
  const int nt = qt + 1;

  for (int kt = 0; kt < nt; ++kt) {
    __syncthreads();
    {  // stage K transposed: KVs[d][c]
      const int c = tid >> 2, d0 = (tid & 3) << 2;
      const float* src = Kp + (size_t)(kt * 64 + c) * kstr;
#pragma unroll
      for (int p = 0; p < 8; ++p) {
        int d = d0 + p * 16;
        float4 v = *(const float4*)(src + d);
        KVs[(d + 0) * 64 + c] = v.x;
        KVs[(d + 1) * 64 + c] = v.y;
        KVs[(d + 2) * 64 + c] = v.z;
        KVs[(d + 3) * 64 + c] = v.w;
      }
    }
    __syncthreads();

    float s[4][4] = {{0.f}};
#pragma unroll 8
    for (int d = 0; d < 128; ++d) {
      float4 qa = *(const float4*)(&Qs[d * 64 + r0]);
      float4 ka = *(const float4*)(&KVs[d * 64 + c0]);
      float qv[4] = {qa.x, qa.y, qa.z, qa.w};
      float kv[4] = {ka.x, ka.y, ka.z, ka.w};
#pragma unroll
      for (int i = 0; i < 4; ++i)
#pragma unroll
        for (int j = 0; j < 4; ++j)
          s[i][j] = fmaf(qv[i], kv[j], s[i][j]);
    }

    if (kt == qt) {
#pragma unroll
      for (int i = 0; i < 4; ++i)
#pragma unroll
        for (int j = 0; j < 4; ++j)
          if (c0 + j > r0 + i) s[i][j] = -1e30f;
    }

    float al[4];
#pragma unroll
    for (int i = 0; i < 4; ++i) {
      float m = fmaxf(fmaxf(s[i][0], s[i][1]), fmaxf(s[i][2], s[i][3]));
      m = fmaxf(m, __shfl_xor(m, 1));
      m = fmaxf(m, __shfl_xor(m, 2));
      m = fmaxf(m, __shfl_xor(m, 4));
      m = fmaxf(m, __shfl_xor(m, 8));
      float mn = fmaxf(mrow[i], m);
      al[i] = __expf(mrow[i] - mn);
      mrow[i] = mn;
      float rsum = 0.f;
#pragma unroll
      for (int j = 0; j < 4; ++j) { s[i][j] = __expf(s[i][j] - mn); rsum += s[i][j]; }
      rsum += __shfl_xor(rsum, 1);
      rsum += __shfl_xor(rsum, 2);
      rsum += __shfl_xor(rsum, 4);
      rsum += __shfl_xor(rsum, 8);
      lrow[i] = lrow[i] * al[i] + rsum;
#pragma unroll
      for (int j = 0; j < 8; ++j) acc[i][j] *= al[i];
    }
    __syncthreads();

#pragma unroll
    for (int j = 0; j < 4; ++j) {
      float4 w4 = {s[0][j], s[1][j], s[2][j], s[3][j]};
      *(float4*)(&Pt[(c0 + j) * 64 + r0]) = w4;
    }
    {
      const int dv = (tid & 31) << 2, cl = tid >> 5;
#pragma unroll
      for (int p = 0; p < 8; ++p) {
        int c = cl + p * 8;
        *(float4*)(&KVs[c * 128 + dv]) =
            *(const float4*)(Vp + (size_t)(kt * 64 + c) * kstr + dv);
      }
    }
    __syncthreads();

#pragma unroll 4
    for (int c = 0; c < 64; ++c) {
      float4 pv  = *(const float4*)(&Pt[c * 64 + r0]);
      float4 va  = *(const float4*)(&KVs[c * 128 + c0]);
      float4 vb2 = *(const float4*)(&KVs[c * 128 + 64 + c0]);
      float pr[4] = {pv.x, pv.y, pv.z, pv.w};
      float va_[4] = {va.x, va.y, va.z, va.w};
      float vb_[4] = {vb2.x, vb2.y, vb2.z, vb2.w};
#pragma unroll
      for (int i = 0; i < 4; ++i) {
#pragma unroll
        for (int j = 0; j < 4; ++j) {
          acc[i][j]     = fmaf(pr[i], va_[j], acc[i][j]);
          acc[i][j + 4] = fmaf(pr[i], vb_[j], acc[i][j + 4]);
        }
      }
    }
  }

#pragma unroll
  for (int i = 0; i < 4; ++i) {
    float inv = 1.0f / lrow[i];
    const size_t orow = (size_t)(b * S + q0 + r0 + i) * qstr + (size_t)h * D_;
    float4 o1 = {acc[i][0] * inv, acc[i][1] * inv, acc[i][2] * inv, acc[i][3] * inv};
    float4 o2 = {acc[i][4] * inv, acc[i][5] * inv, acc[i][6] * inv, acc[i][7] * inv};
    *(float4*)(O + orow + c0) = o1;
    *(float4*)(O + orow + 64 + c0) = o2;
  }
}

extern "C" void kernel_launch(void* const* d_in, const int* in_sizes, int n_in,
                              void* d_out, int out_size, void* d_ws, size_t ws_size,
                              hipStream_t stream) {
  const float* x  = (const float*)d_in[0];
  const float* sn = (const float*)d_in[1];   // sin
  const float* cs = (const float*)d_in[2];   // cos
  // d_in[3] = attention_mask: causal, applied analytically -> unused
  const float* Wq = (const float*)d_in[4];
  const float* Wk = (const float*)d_in[5];
  const float* Wv = (const float*)d_in[6];
  const float* Wo = (const float*)d_in[7];
  const float* qw = (const float*)d_in[8];
  const float* kw = (const float*)d_in[9];
  float* out = (float*)d_out;

  const int BS = in_sizes[0] / HID_;   // B*S = 4096
  const int S  = in_sizes[3] / BS;     // 2048
  const int B  = BS / S;

  // workspace layout
  float* kbuf = (float*)d_ws;                          // BS*KV*D   f32 (16 MB)
  float* vbuf = kbuf + (size_t)BS * KV_ * D_;          // BS*KV*D   f32 (16 MB)
  float* abuf = vbuf + (size_t)BS * KV_ * D_;          // BS*H*D    f32 (32 MB)
  unsigned short* xb   = (unsigned short*)(abuf + (size_t)BS * H_ * D_);  // BS*HID bf16 (16 MB)
  unsigned short* wbuf = xb + (size_t)BS * HID_;       // 4M bf16 (8 MB), reused per weight
  unsigned short* ab16 = xb;                           // reuse xb after QKV GEMMs

  dim3 blk(256);
  const int n8x = BS * HID_ / 8;

  // x -> bf16
  f32_to_bf16<<<dim3(n8x / 256), blk, 0, stream>>>(x, xb, n8x);

  // Q = x @ Wq   (transpose+convert weight, then MFMA GEMM; q lives in d_out)
  transpose_bf16<<<dim3((H_ * D_) / 32, HID_ / 32), blk, 0, stream>>>(Wq, wbuf, HID_, H_ * D_);
  gemm_bf16<<<dim3((H_ * D_) / TBN, BS / TBM), blk, 0, stream>>>(xb, wbuf, out, BS, H_ * D_, HID_);

  // K = x @ Wk
  transpose_bf16<<<dim3((KV_ * D_) / 32, HID_ / 32), blk, 0, stream>>>(Wk, wbuf, HID_, KV_ * D_);
  gemm_bf16<<<dim3((KV_ * D_) / TBN, BS / TBM), blk, 0, stream>>>(xb, wbuf, kbuf, BS, KV_ * D_, HID_);

  // V = x @ Wv
  transpose_bf16<<<dim3((KV_ * D_) / 32, HID_ / 32), blk, 0, stream>>>(Wv, wbuf, HID_, KV_ * D_);
  gemm_bf16<<<dim3((KV_ * D_) / TBN, BS / TBM), blk, 0, stream>>>(xb, wbuf, vbuf, BS, KV_ * D_, HID_);

  // per-head RMSNorm + RoPE (fp32, in place)
  rmsnorm_rope<<<dim3(BS * H_ / 4),  blk, 0, stream>>>(out,  qw, cs, sn, H_);
  rmsnorm_rope<<<dim3(BS * KV_ / 4), blk, 0, stream>>>(kbuf, kw, cs, sn, KV_);

  // causal flash attention (fp32, unchanged)
  flash_f32<<<dim3(S / 64, H_, B), blk, 0, stream>>>(out, kbuf, vbuf, abuf, S, H_ / KV_);

  // attn output -> bf16, then Out = abuf @ Wo
  f32_to_bf16<<<dim3(n8x / 256), blk, 0, stream>>>(abuf, ab16, n8x);
  transpose_bf16<<<dim3(HID_ / 32, (H_ * D_) / 32), blk, 0, stream>>>(Wo, wbuf, H_ * D_, HID_);
  gemm_bf16<<<dim3(HID_ / TBN, BS / TBM), blk, 0, stream>>>(ab16, wbuf, out, BS, HID_, HID_);
}

// Round 4
// 525.557 us; speedup vs baseline: 4.6255x; 2.3481x over previous
//
#include <hip/hip_runtime.h>
#include <hip/hip_bf16.h>
#include <math.h>

#define H_    16
#define KV_   8
#define D_    128
#define HID_  2048
#define SCALE_ 0.08838834764831845f   // 128^-0.5

typedef __attribute__((ext_vector_type(8))) short bf16x8;
typedef __attribute__((ext_vector_type(4))) float f32x4;
typedef __attribute__((ext_vector_type(4))) short short4v;

__device__ inline unsigned short f2bf(float f) {
  unsigned u = __builtin_bit_cast(unsigned, f);
  u += 0x7FFF + ((u >> 16) & 1);   // RNE
  return (unsigned short)(u >> 16);
}

#define GLDS16(g, l)                                                     \
  __builtin_amdgcn_global_load_lds(                                      \
      (const __attribute__((address_space(1))) void*)(g),                \
      (__attribute__((address_space(3))) void*)(l), 16, 0, 0)

// ---------------- f32 -> bf16 (contiguous, x8 per thread) ----------------
__global__ __launch_bounds__(256) void f32_to_bf16(
    const float* __restrict__ in, unsigned short* __restrict__ out, int n8) {
  int i = blockIdx.x * 256 + threadIdx.x;
  if (i >= n8) return;
  const float4* p = (const float4*)in + (size_t)i * 2;
  float4 a = p[0], b = p[1];
  unsigned short o[8] = {f2bf(a.x), f2bf(a.y), f2bf(a.z), f2bf(a.w),
                         f2bf(b.x), f2bf(b.y), f2bf(b.z), f2bf(b.w)};
  *(bf16x8*)(out + (size_t)i * 8) = *(bf16x8*)o;
}

// ------------- f32 (K x N) -> bf16 transposed (N x K) -------------
__global__ __launch_bounds__(256) void transpose_bf16(
    const float* __restrict__ in, unsigned short* __restrict__ out, int K, int N) {
  __shared__ float t[32][33];
  const int k0 = blockIdx.y * 32, n0 = blockIdx.x * 32;
  const int r = threadIdx.x >> 3, c4 = (threadIdx.x & 7) * 4;
  float4 v = *(const float4*)(in + (size_t)(k0 + r) * N + n0 + c4);
  t[r][c4 + 0] = v.x; t[r][c4 + 1] = v.y; t[r][c4 + 2] = v.z; t[r][c4 + 3] = v.w;
  __syncthreads();
  unsigned short o[4];
#pragma unroll
  for (int j = 0; j < 4; ++j) o[j] = f2bf(t[c4 + j][r]);
  *(short4v*)(out + (size_t)(n0 + r) * K + k0 + c4) = *(short4v*)o;
}

// ---------------- bf16 MFMA GEMM: C(M,N) = A(M,K) @ Bt(N,K)^T ----------------
// EPI 0: C f32 row-major.  EPI 2: C bf16 written as V^T: [b*KV+(col>>7)][col&127][s]
#define TBM 128
#define TBN 128
#define TBK 64

template <int EPI>
__global__ __launch_bounds__(256) void gemm_bf16(
    const unsigned short* __restrict__ A,   // M x K row-major
    const unsigned short* __restrict__ Bt,  // N x K row-major
    void* __restrict__ Cv, int M, int N, int K, int S) {
  __shared__ unsigned short As[TBM * TBK];  // [m][k], 16 KB
  __shared__ unsigned short Bs[TBN * TBK];  // [n][k], 16 KB
  const int tid = threadIdx.x;
  const int w = tid >> 6, lane = tid & 63;
  const int wm = w >> 1, wn = w & 1;
  const int fr = lane & 15, fq = lane >> 4;
  const int row0 = blockIdx.y * TBM, col0 = blockIdx.x * TBN;

  const unsigned short* Ab = A + (size_t)row0 * K;
  const unsigned short* Bb = Bt + (size_t)col0 * K;
  const int sm = lane >> 3;         // row within 8-row segment
  const int sk = (lane & 7) * 8;    // k offset (8 elems = 16B)

  f32x4 acc[4][4] = {};

  for (int k0 = 0; k0 < K; k0 += TBK) {
    __syncthreads();
#pragma unroll
    for (int p = 0; p < 4; ++p) {
      const int seg = w * 4 + p;            // 0..15, wave-uniform
      const int m = seg * 8 + sm;
      GLDS16(Ab + (size_t)m * K + k0 + sk, As + seg * 512);
      GLDS16(Bb + (size_t)m * K + k0 + sk, Bs + seg * 512);
    }
    __syncthreads();
#pragma unroll
    for (int s = 0; s < 2; ++s) {
      bf16x8 af[4], bfr[4];
#pragma unroll
      for (int i = 0; i < 4; ++i)
        af[i] = *(const bf16x8*)(As + (wm * 64 + i * 16 + fr) * TBK + s * 32 + fq * 8);
#pragma unroll
      for (int j = 0; j < 4; ++j)
        bfr[j] = *(const bf16x8*)(Bs + (wn * 64 + j * 16 + fr) * TBK + s * 32 + fq * 8);
#pragma unroll
      for (int i = 0; i < 4; ++i)
#pragma unroll
        for (int j = 0; j < 4; ++j)
          acc[i][j] = __builtin_amdgcn_mfma_f32_16x16x32_bf16(af[i], bfr[j], acc[i][j], 0, 0, 0);
    }
  }

  if constexpr (EPI == 0) {
    float* C = (float*)Cv;
#pragma unroll
    for (int i = 0; i < 4; ++i)
#pragma unroll
      for (int j = 0; j < 4; ++j) {
        const int col = col0 + wn * 64 + j * 16 + fr;
#pragma unroll
        for (int r = 0; r < 4; ++r) {
          const int row = row0 + wm * 64 + i * 16 + fq * 4 + r;
          C[(size_t)row * N + col] = acc[i][j][r];
        }
      }
  } else {  // V^T bf16 epilogue
    unsigned short* C = (unsigned short*)Cv;
#pragma unroll
    for (int i = 0; i < 4; ++i)
#pragma unroll
      for (int j = 0; j < 4; ++j) {
        const int col = col0 + wn * 64 + j * 16 + fr;
        const int kvh = col >> 7, d = col & 127;
        const int row = row0 + wm * 64 + i * 16 + fq * 4;   // 4 consecutive s
        const int b = row / S, s = row - b * S;
        unsigned short o[4] = {f2bf(acc[i][j][0]), f2bf(acc[i][j][1]),
                               f2bf(acc[i][j][2]), f2bf(acc[i][j][3])};
        *(short4v*)(C + ((size_t)(b * KV_ + kvh) * D_ + d) * S + s) = *(short4v*)o;
      }
  }
}

// ------- fused per-head RMSNorm + RoPE: f32 in, bf16 out (same layout) -------
__global__ __launch_bounds__(256) void rmsnorm_rope_o16(
    const float* __restrict__ p, unsigned short* __restrict__ o16,
    const float* __restrict__ w, const float* __restrict__ cs,
    const float* __restrict__ sn, int nheads) {
  const int row  = blockIdx.x * 4 + (threadIdx.x >> 6);
  const int lane = threadIdx.x & 63;
  const float* base = p + (size_t)row * D_;
  float x1 = base[lane];
  float x2 = base[lane + 64];
  float ss = x1 * x1 + x2 * x2;
#pragma unroll
  for (int m = 32; m; m >>= 1) ss += __shfl_xor(ss, m);
  float r = rsqrtf(ss * (1.0f / 128.0f) + 1e-6f);
  const size_t sidx = (size_t)(row / nheads) * D_;
  float n1 = x1 * r * w[lane];
  float n2 = x2 * r * w[lane + 64];
  unsigned short* ob = o16 + (size_t)row * D_;
  ob[lane]      = f2bf(n1 * cs[sidx + lane]      - n2 * sn[sidx + lane]);
  ob[lane + 64] = f2bf(n2 * cs[sidx + lane + 64] + n1 * sn[sidx + lane + 64]);
}

// ------------- bf16 MFMA causal flash attention, GQA -------------
// Qb: (B*S, H, D) bf16 post-norm/rope; Kb: (B*S, KV, D) bf16; Vt: (B*KV, D, S) bf16
// O: (B*S, H*D) bf16
__global__ __launch_bounds__(256) void flash_bf16(
    const unsigned short* __restrict__ Qb, const unsigned short* __restrict__ Kb,
    const unsigned short* __restrict__ Vt, unsigned short* __restrict__ O, int S) {
  __shared__ unsigned short Kt[64 * 128];   // [kv][d], chunk-swizzled, 16 KB
  __shared__ unsigned short Vs[128 * 64];   // [d][kv], chunk-swizzled, 16 KB
  __shared__ unsigned short Pl[4][16 * 64]; // per-wave P [q][kv], swizzled, 2 KB each
  const int qt = blockIdx.x, h = blockIdx.y, b = blockIdx.z;
  const int kvh = h >> 1;                   // groups = H/KV = 2
  const int tid = threadIdx.x, w = tid >> 6, lane = tid & 63;
  const int fr = lane & 15, fq = lane >> 4;
  const int q0 = qt * 64;

  // Q A-fragments in registers: rows = fr (wave-local), 4 k-steps of 32
  bf16x8 qf[4];
  {
    const unsigned short* qp =
        Qb + ((size_t)(b * S + q0 + w * 16 + fr) * H_ + h) * D_;
#pragma unroll
    for (int s = 0; s < 4; ++s) qf[s] = *(const bf16x8*)(qp + s * 32 + fq * 8);
  }

  const unsigned short* vhead = Vt + (size_t)(b * KV_ + kvh) * D_ * S;

  f32x4 acco[8] = {};   // O[q=fq*4+r][d=16c+fr]
  float mrow[4] = {-1e30f, -1e30f, -1e30f, -1e30f};
  float lrow[4] = {0.f, 0.f, 0.f, 0.f};

  for (int kt = 0; kt <= qt; ++kt) {
    __syncthreads();   // prev tile's LDS reads done
    // ---- stage K [64][128] and V^T [128][64], pre-swizzled global source ----
#pragma unroll
    for (int p = 0; p < 4; ++p) {
      const int seg = w * 4 + p;
      {  // K: 4 rows/seg, 16 chunks of 8 elems per row
        const int kv = seg * 4 + (lane >> 4);
        const int ch = lane & 15;
        const int gch = (ch & 8) | ((ch ^ kv) & 7);
        GLDS16(Kb + ((size_t)(b * S + kt * 64 + kv) * KV_ + kvh) * D_ + gch * 8,
               Kt + seg * 512);
      }
      {  // V^T: 8 rows/seg, 8 chunks per row
        const int d = seg * 8 + (lane >> 3);
        const int c = lane & 7;
        const int gc = c ^ (d & 7);
        GLDS16(vhead + (size_t)d * S + kt * 64 + gc * 8, Vs + seg * 512);
      }
    }
    __syncthreads();   // vmcnt drained by compiler before barrier

    // ---- S = Q @ K^T  (C: row=q=fq*4+r, col=kv=16t+fr) ----
    f32x4 sa[4];
#pragma unroll
    for (int t = 0; t < 4; ++t) {
      f32x4 a = {};
      const int kv = 16 * t + fr;
#pragma unroll
      for (int s = 0; s < 4; ++s) {
        const int ch = 4 * s + fq;
        const int chs = (ch & 8) | ((ch ^ kv) & 7);
        bf16x8 kf = *(const bf16x8*)(Kt + kv * 128 + chs * 8);
        a = __builtin_amdgcn_mfma_f32_16x16x32_bf16(qf[s], kf, a, 0, 0, 0);
      }
      sa[t] = a;
    }

    // scale + causal mask (diagonal tile)
#pragma unroll
    for (int t = 0; t < 4; ++t)
#pragma unroll
      for (int r = 0; r < 4; ++r) sa[t][r] *= SCALE_;
    if (kt == qt) {
#pragma unroll
      for (int t = 0; t < 4; ++t) {
        const int kvl = 16 * t + fr;
#pragma unroll
        for (int r = 0; r < 4; ++r)
          if (kvl > w * 16 + fq * 4 + r) sa[t][r] = -1e30f;
      }
    }

    // ---- online softmax (rows owned per reg r; reduce across fr lanes) ----
    float al[4];
#pragma unroll
    for (int r = 0; r < 4; ++r) {
      float mx = fmaxf(fmaxf(sa[0][r], sa[1][r]), fmaxf(sa[2][r], sa[3][r]));
      mx = fmaxf(mx, __shfl_xor(mx, 1));
      mx = fmaxf(mx, __shfl_xor(mx, 2));
      mx = fmaxf(mx, __shfl_xor(mx, 4));
      mx = fmaxf(mx, __shfl_xor(mx, 8));
      const float mn = fmaxf(mrow[r], mx);
      al[r] = __expf(mrow[r] - mn);
      mrow[r] = mn;
      float sum = 0.f;
#pragma unroll
      for (int t = 0; t < 4; ++t) {
        const float pv = __expf(sa[t][r] - mn);
        sa[t][r] = pv;
        sum += pv;
      }
      sum += __shfl_xor(sum, 1);
      sum += __shfl_xor(sum, 2);
      sum += __shfl_xor(sum, 4);
      sum += __shfl_xor(sum, 8);
      lrow[r] = lrow[r] * al[r] + sum;
#pragma unroll
      for (int c = 0; c < 8; ++c) acco[c][r] *= al[r];
    }

    // ---- P -> per-wave LDS (bf16, chunk-swizzled) ----
    unsigned short* pw = &Pl[w][0];
#pragma unroll
    for (int t = 0; t < 4; ++t) {
      const int kv = 16 * t + fr;
      const int ch = kv >> 3;
#pragma unroll
      for (int r = 0; r < 4; ++r) {
        const int q = fq * 4 + r;
        pw[q * 64 + ((ch ^ q) & 7) * 8 + (kv & 7)] = f2bf(sa[t][r]);
      }
    }

    // ---- O += P @ V  (A = P[q=fr][kv], B = V^T rows) ----
    bf16x8 pf[2];
#pragma unroll
    for (int s = 0; s < 2; ++s)
      pf[s] = *(const bf16x8*)(pw + fr * 64 + (((4 * s + fq) ^ fr) & 7) * 8);
#pragma unroll
    for (int c = 0; c < 8; ++c) {
      const int d = 16 * c + fr;
#pragma unroll
      for (int s = 0; s < 2; ++s) {
        bf16x8 vf = *(const bf16x8*)(Vs + d * 64 + (((4 * s + fq) ^ d) & 7) * 8);
        acco[c] = __builtin_amdgcn_mfma_f32_16x16x32_bf16(pf[s], vf, acco[c], 0, 0, 0);
      }
    }
  }

  // ---- epilogue: O = acc / l, bf16 ----
  float inv[4];
#pragma unroll
  for (int r = 0; r < 4; ++r) inv[r] = 1.0f / lrow[r];
#pragma unroll
  for (int c = 0; c < 8; ++c) {
#pragma unroll
    for (int r = 0; r < 4; ++r) {
      const int q = q0 + w * 16 + fq * 4 + r;
      O[(size_t)(b * S + q) * (H_ * D_) + h * D_ + 16 * c + fr] =
          f2bf(acco[c][r] * inv[r]);
    }
  }
}

extern "C" void kernel_launch(void* const* d_in, const int* in_sizes, int n_in,
                              void* d_out, int out_size, void* d_ws, size_t ws_size,
                              hipStream_t stream) {
  const float* x  = (const float*)d_in[0];
  const float* sn = (const float*)d_in[1];   // sin
  const float* cs = (const float*)d_in[2];   // cos
  // d_in[3] = attention_mask: causal, applied analytically -> unused
  const float* Wq = (const float*)d_in[4];
  const float* Wk = (const float*)d_in[5];
  const float* Wv = (const float*)d_in[6];
  const float* Wo = (const float*)d_in[7];
  const float* qw = (const float*)d_in[8];
  const float* kw = (const float*)d_in[9];
  float* out = (float*)d_out;

  const int BS = in_sizes[0] / HID_;   // B*S = 4096
  const int S  = in_sizes[3] / BS;     // 2048
  const int B  = BS / S;

  // workspace layout (88 MB total)
  float* kbuf = (float*)d_ws;                                  // BS*KV*D f32  16 MB
  unsigned short* vt   = (unsigned short*)(kbuf + (size_t)BS * KV_ * D_);  // 8 MB
  unsigned short* xb   = vt + (size_t)BS * KV_ * D_;           // BS*HID bf16  16 MB
  unsigned short* wbuf = xb + (size_t)BS * HID_;               // 4M bf16       8 MB
  unsigned short* qb   = wbuf + (size_t)HID_ * HID_;           // BS*H*D bf16  16 MB
  unsigned short* kb16 = qb + (size_t)BS * H_ * D_;            // BS*KV*D bf16  8 MB
  unsigned short* ab16 = kb16 + (size_t)BS * KV_ * D_;         // BS*H*D bf16  16 MB

  dim3 blk(256);
  const int n8x = BS * HID_ / 8;

  // x -> bf16
  f32_to_bf16<<<dim3(n8x / 256), blk, 0, stream>>>(x, xb, n8x);

  // Q = x @ Wq (f32 into d_out)
  transpose_bf16<<<dim3((H_ * D_) / 32, HID_ / 32), blk, 0, stream>>>(Wq, wbuf, HID_, H_ * D_);
  gemm_bf16<0><<<dim3((H_ * D_) / TBN, BS / TBM), blk, 0, stream>>>(xb, wbuf, out, BS, H_ * D_, HID_, S);

  // K = x @ Wk (f32 into kbuf)
  transpose_bf16<<<dim3((KV_ * D_) / 32, HID_ / 32), blk, 0, stream>>>(Wk, wbuf, HID_, KV_ * D_);
  gemm_bf16<0><<<dim3((KV_ * D_) / TBN, BS / TBM), blk, 0, stream>>>(xb, wbuf, kbuf, BS, KV_ * D_, HID_, S);

  // V = x @ Wv (bf16 V^T directly into vt)
  transpose_bf16<<<dim3((KV_ * D_) / 32, HID_ / 32), blk, 0, stream>>>(Wv, wbuf, HID_, KV_ * D_);
  gemm_bf16<2><<<dim3((KV_ * D_) / TBN, BS / TBM), blk, 0, stream>>>(xb, wbuf, vt, BS, KV_ * D_, HID_, S);

  // per-head RMSNorm + RoPE -> bf16
  rmsnorm_rope_o16<<<dim3(BS * H_ / 4),  blk, 0, stream>>>(out,  qb,   qw, cs, sn, H_);
  rmsnorm_rope_o16<<<dim3(BS * KV_ / 4), blk, 0, stream>>>(kbuf, kb16, kw, cs, sn, KV_);

  // causal MFMA flash attention -> bf16
  flash_bf16<<<dim3(S / 64, H_, B), blk, 0, stream>>>(qb, kb16, vt, ab16, S);

  // Out = abuf @ Wo (f32 into d_out)
  transpose_bf16<<<dim3(HID_ / 32, (H_ * D_) / 32), blk, 0, stream>>>(Wo, wbuf, H_ * D_, HID_);
  gemm_bf16<0><<<dim3(HID_ / TBN, BS / TBM), blk, 0, stream>>>(ab16, wbuf, out, BS, HID_, HID_, S);
}

// Round 6
// 426.063 us; speedup vs baseline: 5.7057x; 1.2335x over previous
//
#include <hip/hip_runtime.h>
#include <hip/hip_bf16.h>
#include <math.h>

#define H_    16
#define KV_   8
#define D_    128
#define HID_  2048
#define NQKV_ 4096   // H*D + KV*D + KV*D
#define SCALE_ 0.08838834764831845f   // 128^-0.5

typedef __attribute__((ext_vector_type(8))) short bf16x8;
typedef __attribute__((ext_vector_type(4))) float f32x4;
typedef __attribute__((ext_vector_type(4))) short short4v;

__device__ inline unsigned short f2bf(float f) {
  unsigned u = __builtin_bit_cast(unsigned, f);
  u += 0x7FFF + ((u >> 16) & 1);   // RNE
  return (unsigned short)(u >> 16);
}

#define GLDS16(g, l)                                                     \
  __builtin_amdgcn_global_load_lds(                                      \
      (const __attribute__((address_space(1))) void*)(g),                \
      (__attribute__((address_space(3))) void*)(l), 16, 0, 0)

// ---------------- f32 -> bf16 (contiguous, x8 per thread) ----------------
__global__ __launch_bounds__(256) void f32_to_bf16(
    const float* __restrict__ in, unsigned short* __restrict__ out, int n8) {
  int i = blockIdx.x * 256 + threadIdx.x;
  if (i >= n8) return;
  const float4* p = (const float4*)in + (size_t)i * 2;
  float4 a = p[0], b = p[1];
  unsigned short o[8] = {f2bf(a.x), f2bf(a.y), f2bf(a.z), f2bf(a.w),
                         f2bf(b.x), f2bf(b.y), f2bf(b.z), f2bf(b.w)};
  *(bf16x8*)(out + (size_t)i * 8) = *(bf16x8*)o;
}

// ------------- f32 (K x N) -> bf16 transposed (N x K) -------------
__global__ __launch_bounds__(256) void transpose_bf16(
    const float* __restrict__ in, unsigned short* __restrict__ out, int K, int N) {
  __shared__ float t[32][33];
  const int k0 = blockIdx.y * 32, n0 = blockIdx.x * 32;
  const int r = threadIdx.x >> 3, c4 = (threadIdx.x & 7) * 4;
  float4 v = *(const float4*)(in + (size_t)(k0 + r) * N + n0 + c4);
  t[r][c4 + 0] = v.x; t[r][c4 + 1] = v.y; t[r][c4 + 2] = v.z; t[r][c4 + 3] = v.w;
  __syncthreads();
  unsigned short o[4];
#pragma unroll
  for (int j = 0; j < 4; ++j) o[j] = f2bf(t[c4 + j][r]);
  *(short4v*)(out + (size_t)(n0 + r) * K + k0 + c4) = *(short4v*)o;
}

// ---------------- bf16 MFMA GEMM: C = A(M,K) @ Bt(N,K)^T ----------------
// EPI 0: C0 f32 row-major (ld = N).
// EPI 1: fused QKV epilogue: col<2048 -> Q f32 (C0, ld 2048);
//        col<3072 -> K f32 (C1, ld 1024); else V^T bf16 (C2).
#define TBM 128
#define TBN 128
#define TBK 64

template <int EPI>
__global__ __launch_bounds__(256) void gemm_bf16(
    const unsigned short* __restrict__ A,   // M x K row-major
    const unsigned short* __restrict__ Bt,  // N x K row-major
    float* __restrict__ C0, float* __restrict__ C1,
    unsigned short* __restrict__ C2, int M, int N, int K, int S) {
  __shared__ unsigned short As[TBM * TBK];  // [m][k], 16 KB
  __shared__ unsigned short Bs[TBN * TBK];  // [n][k], 16 KB
  const int tid = threadIdx.x;
  const int w = tid >> 6, lane = tid & 63;
  const int wm = w >> 1, wn = w & 1;
  const int fr = lane & 15, fq = lane >> 4;
  const int row0 = blockIdx.y * TBM, col0 = blockIdx.x * TBN;

  const unsigned short* Ab = A + (size_t)row0 * K;
  const unsigned short* Bb = Bt + (size_t)col0 * K;
  const int sm = lane >> 3;         // row within 8-row segment
  const int sk = (lane & 7) * 8;    // k offset (8 elems = 16B)

  f32x4 acc[4][4] = {};

  for (int k0 = 0; k0 < K; k0 += TBK) {
    __syncthreads();
#pragma unroll
    for (int p = 0; p < 4; ++p) {
      const int seg = w * 4 + p;            // 0..15, wave-uniform
      const int m = seg * 8 + sm;
      GLDS16(Ab + (size_t)m * K + k0 + sk, As + seg * 512);
      GLDS16(Bb + (size_t)m * K + k0 + sk, Bs + seg * 512);
    }
    __syncthreads();
#pragma unroll
    for (int s = 0; s < 2; ++s) {
      bf16x8 af[4], bfr[4];
#pragma unroll
      for (int i = 0; i < 4; ++i)
        af[i] = *(const bf16x8*)(As + (wm * 64 + i * 16 + fr) * TBK + s * 32 + fq * 8);
#pragma unroll
      for (int j = 0; j < 4; ++j)
        bfr[j] = *(const bf16x8*)(Bs + (wn * 64 + j * 16 + fr) * TBK + s * 32 + fq * 8);
#pragma unroll
      for (int i = 0; i < 4; ++i)
#pragma unroll
        for (int j = 0; j < 4; ++j)
          acc[i][j] = __builtin_amdgcn_mfma_f32_16x16x32_bf16(af[i], bfr[j], acc[i][j], 0, 0, 0);
    }
  }

  // C/D layout (m89-verified): col = lane&15, row = (lane>>4)*4 + reg
  if constexpr (EPI == 0) {
#pragma unroll
    for (int i = 0; i < 4; ++i)
#pragma unroll
      for (int j = 0; j < 4; ++j) {
        const int col = col0 + wn * 64 + j * 16 + fr;
#pragma unroll
        for (int r = 0; r < 4; ++r) {
          const int row = row0 + wm * 64 + i * 16 + fq * 4 + r;
          C0[(size_t)row * N + col] = acc[i][j][r];
        }
      }
  } else {  // fused QKV
    if (col0 < H_ * D_) {  // Q: f32 row-major, ld = 2048
#pragma unroll
      for (int i = 0; i < 4; ++i)
#pragma unroll
        for (int j = 0; j < 4; ++j) {
          const int col = col0 + wn * 64 + j * 16 + fr;
#pragma unroll
          for (int r = 0; r < 4; ++r) {
            const int row = row0 + wm * 64 + i * 16 + fq * 4 + r;
            C0[(size_t)row * (H_ * D_) + col] = acc[i][j][r];
          }
        }
    } else if (col0 < H_ * D_ + KV_ * D_) {  // K: f32 row-major, ld = 1024
#pragma unroll
      for (int i = 0; i < 4; ++i)
#pragma unroll
        for (int j = 0; j < 4; ++j) {
          const int col = col0 - H_ * D_ + wn * 64 + j * 16 + fr;
#pragma unroll
          for (int r = 0; r < 4; ++r) {
            const int row = row0 + wm * 64 + i * 16 + fq * 4 + r;
            C1[(size_t)row * (KV_ * D_) + col] = acc[i][j][r];
          }
        }
    } else {  // V^T bf16: [b*KV+kvh][d][s]
#pragma unroll
      for (int i = 0; i < 4; ++i)
#pragma unroll
        for (int j = 0; j < 4; ++j) {
          const int cc = col0 - (H_ * D_ + KV_ * D_) + wn * 64 + j * 16 + fr;
          const int kvh = cc >> 7, d = cc & 127;
          const int row = row0 + wm * 64 + i * 16 + fq * 4;   // 4 consecutive s
          const int b = row / S, s = row - b * S;
          unsigned short o[4] = {f2bf(acc[i][j][0]), f2bf(acc[i][j][1]),
                                 f2bf(acc[i][j][2]), f2bf(acc[i][j][3])};
          *(short4v*)(C2 + ((size_t)(b * KV_ + kvh) * D_ + d) * S + s) = *(short4v*)o;
        }
    }
  }
}

// ------- fused per-head RMSNorm + RoPE: f32 in, bf16 out (same layout) -------
__global__ __launch_bounds__(256) void rmsnorm_rope_o16(
    const float* __restrict__ p, unsigned short* __restrict__ o16,
    const float* __restrict__ w, const float* __restrict__ cs,
    const float* __restrict__ sn, int nheads) {
  const int row  = blockIdx.x * 4 + (threadIdx.x >> 6);
  const int lane = threadIdx.x & 63;
  const float* base = p + (size_t)row * D_;
  float x1 = base[lane];
  float x2 = base[lane + 64];
  float ss = x1 * x1 + x2 * x2;
#pragma unroll
  for (int m = 32; m; m >>= 1) ss += __shfl_xor(ss, m);
  float r = rsqrtf(ss * (1.0f / 128.0f) + 1e-6f);
  const size_t sidx = (size_t)(row / nheads) * D_;
  float n1 = x1 * r * w[lane];
  float n2 = x2 * r * w[lane + 64];
  unsigned short* ob = o16 + (size_t)row * D_;
  ob[lane]      = f2bf(n1 * cs[sidx + lane]      - n2 * sn[sidx + lane]);
  ob[lane + 64] = f2bf(n2 * cs[sidx + lane + 64] + n1 * sn[sidx + lane + 64]);
}

// ------------- bf16 MFMA causal flash attention, GQA, work-balanced -------------
// Each block processes q-tiles {bid, nqt-1-bid}: uniform 33-tile work, no tail.
// Qb: (B*S, H, D) bf16; Kb: (B*S, KV, D) bf16; Vt: (B*KV, D, S) bf16; O bf16.
__global__ __launch_bounds__(256) void flash_bf16(
    const unsigned short* __restrict__ Qb, const unsigned short* __restrict__ Kb,
    const unsigned short* __restrict__ Vt, unsigned short* __restrict__ O,
    int S, int nqt) {
  __shared__ unsigned short Kt[64 * 128];   // [kv][d], chunk-swizzled, 16 KB
  __shared__ unsigned short Vs[128 * 64];   // [d][kv], chunk-swizzled, 16 KB
  __shared__ unsigned short Pl[4][16 * 64]; // per-wave P [q][kv], swizzled, 2 KB each
  const int h = blockIdx.y, b = blockIdx.z;
  const int kvh = h >> 1;                   // groups = H/KV = 2
  const int tid = threadIdx.x, w = tid >> 6, lane = tid & 63;
  const int fr = lane & 15, fq = lane >> 4;
  const unsigned short* vhead = Vt + (size_t)(b * KV_ + kvh) * D_ * S;

#pragma unroll 1
  for (int half = 0; half < 2; ++half) {
    const int qt = half ? (nqt - 1 - (int)blockIdx.x) : (int)blockIdx.x;
    const int q0 = qt * 64;

    // Q A-fragments in registers: rows = fr (wave-local), 4 k-steps of 32
    bf16x8 qf[4];
    {
      const unsigned short* qp =
          Qb + ((size_t)(b * S + q0 + w * 16 + fr) * H_ + h) * D_;
#pragma unroll
      for (int s = 0; s < 4; ++s) qf[s] = *(const bf16x8*)(qp + s * 32 + fq * 8);
    }

    f32x4 acco[8] = {};   // O[q=fq*4+r][d=16c+fr]
    float mrow[4] = {-1e30f, -1e30f, -1e30f, -1e30f};
    float lrow[4] = {0.f, 0.f, 0.f, 0.f};

    for (int kt = 0; kt <= qt; ++kt) {
      __syncthreads();   // prev tile's (or prev half's) LDS reads done
      // ---- stage K [64][128] and V^T [128][64], pre-swizzled global source ----
#pragma unroll
      for (int p = 0; p < 4; ++p) {
        const int seg = w * 4 + p;
        {  // K: 4 rows/seg, 16 chunks of 8 elems per row
          const int kv = seg * 4 + (lane >> 4);
          const int ch = lane & 15;
          const int gch = (ch & 8) | ((ch ^ kv) & 7);
          GLDS16(Kb + ((size_t)(b * S + kt * 64 + kv) * KV_ + kvh) * D_ + gch * 8,
                 Kt + seg * 512);
        }
        {  // V^T: 8 rows/seg, 8 chunks per row
          const int d = seg * 8 + (lane >> 3);
          const int c = lane & 7;
          const int gc = c ^ (d & 7);
          GLDS16(vhead + (size_t)d * S + kt * 64 + gc * 8, Vs + seg * 512);
        }
      }
      __syncthreads();   // vmcnt drained by compiler before barrier

      // ---- S = Q @ K^T  (C: row=q=fq*4+r, col=kv=16t+fr) ----
      f32x4 sa[4];
      __builtin_amdgcn_s_setprio(1);
#pragma unroll
      for (int t = 0; t < 4; ++t) {
        f32x4 a = {};
        const int kv = 16 * t + fr;
#pragma unroll
        for (int s = 0; s < 4; ++s) {
          const int ch = 4 * s + fq;
          const int chs = (ch & 8) | ((ch ^ kv) & 7);
          bf16x8 kf = *(const bf16x8*)(Kt + kv * 128 + chs * 8);
          a = __builtin_amdgcn_mfma_f32_16x16x32_bf16(qf[s], kf, a, 0, 0, 0);
        }
        sa[t] = a;
      }
      __builtin_amdgcn_s_setprio(0);

      // scale + causal mask (diagonal tile)
#pragma unroll
      for (int t = 0; t < 4; ++t)
#pragma unroll
        for (int r = 0; r < 4; ++r) sa[t][r] *= SCALE_;
      if (kt == qt) {
#pragma unroll
        for (int t = 0; t < 4; ++t) {
          const int kvl = 16 * t + fr;
#pragma unroll
          for (int r = 0; r < 4; ++r)
            if (kvl > w * 16 + fq * 4 + r) sa[t][r] = -1e30f;
        }
      }

      // ---- online softmax (rows owned per reg r; reduce across fr lanes) ----
      float al[4];
#pragma unroll
      for (int r = 0; r < 4; ++r) {
        float mx = fmaxf(fmaxf(sa[0][r], sa[1][r]), fmaxf(sa[2][r], sa[3][r]));
        mx = fmaxf(mx, __shfl_xor(mx, 1));
        mx = fmaxf(mx, __shfl_xor(mx, 2));
        mx = fmaxf(mx, __shfl_xor(mx, 4));
        mx = fmaxf(mx, __shfl_xor(mx, 8));
        const float mn = fmaxf(mrow[r], mx);
        al[r] = __expf(mrow[r] - mn);
        mrow[r] = mn;
        float sum = 0.f;
#pragma unroll
        for (int t = 0; t < 4; ++t) {
          const float pv = __expf(sa[t][r] - mn);
          sa[t][r] = pv;
          sum += pv;
        }
        sum += __shfl_xor(sum, 1);
        sum += __shfl_xor(sum, 2);
        sum += __shfl_xor(sum, 4);
        sum += __shfl_xor(sum, 8);
        lrow[r] = lrow[r] * al[r] + sum;
#pragma unroll
        for (int c = 0; c < 8; ++c) acco[c][r] *= al[r];
      }

      // ---- P -> per-wave LDS (bf16, chunk-swizzled) ----
      unsigned short* pw = &Pl[w][0];
#pragma unroll
      for (int t = 0; t < 4; ++t) {
        const int kv = 16 * t + fr;
        const int ch = kv >> 3;
#pragma unroll
        for (int r = 0; r < 4; ++r) {
          const int q = fq * 4 + r;
          pw[q * 64 + ((ch ^ q) & 7) * 8 + (kv & 7)] = f2bf(sa[t][r]);
        }
      }

      // ---- O += P @ V  (A = P[q=fr][kv], B = V^T rows) ----
      bf16x8 pf[2];
#pragma unroll
      for (int s = 0; s < 2; ++s)
        pf[s] = *(const bf16x8*)(pw + fr * 64 + (((4 * s + fq) ^ fr) & 7) * 8);
      __builtin_amdgcn_s_setprio(1);
#pragma unroll
      for (int c = 0; c < 8; ++c) {
        const int d = 16 * c + fr;
#pragma unroll
        for (int s = 0; s < 2; ++s) {
          bf16x8 vf = *(const bf16x8*)(Vs + d * 64 + (((4 * s + fq) ^ d) & 7) * 8);
          acco[c] = __builtin_amdgcn_mfma_f32_16x16x32_bf16(pf[s], vf, acco[c], 0, 0, 0);
        }
      }
      __builtin_amdgcn_s_setprio(0);
    }

    // ---- epilogue: O = acc / l, bf16 ----
    float inv[4];
#pragma unroll
    for (int r = 0; r < 4; ++r) inv[r] = 1.0f / lrow[r];
#pragma unroll
    for (int c = 0; c < 8; ++c) {
#pragma unroll
      for (int r = 0; r < 4; ++r) {
        const int q = q0 + w * 16 + fq * 4 + r;
        O[(size_t)(b * S + q) * (H_ * D_) + h * D_ + 16 * c + fr] =
            f2bf(acco[c][r] * inv[r]);
      }
    }
  }
}

extern "C" void kernel_launch(void* const* d_in, const int* in_sizes, int n_in,
                              void* d_out, int out_size, void* d_ws, size_t ws_size,
                              hipStream_t stream) {
  const float* x  = (const float*)d_in[0];
  const float* sn = (const float*)d_in[1];   // sin
  const float* cs = (const float*)d_in[2];   // cos
  // d_in[3] = attention_mask: causal, applied analytically -> unused
  const float* Wq = (const float*)d_in[4];
  const float* Wk = (const float*)d_in[5];
  const float* Wv = (const float*)d_in[6];
  const float* Wo = (const float*)d_in[7];
  const float* qw = (const float*)d_in[8];
  const float* kw = (const float*)d_in[9];
  float* out = (float*)d_out;

  const int BS = in_sizes[0] / HID_;   // B*S = 4096
  const int S  = in_sizes[3] / BS;     // 2048
  const int B  = BS / S;

  // workspace layout (80 MB total)
  float* kbuf = (float*)d_ws;                                  // BS*KV*D f32  16 MB
  unsigned short* vt   = (unsigned short*)(kbuf + (size_t)BS * KV_ * D_);  // 8 MB
  unsigned short* xb   = vt + (size_t)BS * KV_ * D_;           // BS*HID bf16  16 MB
  unsigned short* wT   = xb + (size_t)BS * HID_;               // 4096*2048 bf16 16 MB
  unsigned short* qb   = wT + (size_t)NQKV_ * HID_;            // BS*H*D bf16  16 MB
  unsigned short* kb16 = qb + (size_t)BS * H_ * D_;            // BS*KV*D bf16  8 MB
  unsigned short* ab16 = xb;                                   // reuse xb after QKV GEMM

  dim3 blk(256);
  const int n8x = BS * HID_ / 8;

  // x -> bf16
  f32_to_bf16<<<dim3(n8x / 256), blk, 0, stream>>>(x, xb, n8x);

  // transpose all three weights into one concatenated (N=4096, K=2048) buffer
  transpose_bf16<<<dim3((H_ * D_) / 32, HID_ / 32), blk, 0, stream>>>(Wq, wT, HID_, H_ * D_);
  transpose_bf16<<<dim3((KV_ * D_) / 32, HID_ / 32), blk, 0, stream>>>(
      Wk, wT + (size_t)(H_ * D_) * HID_, HID_, KV_ * D_);
  transpose_bf16<<<dim3((KV_ * D_) / 32, HID_ / 32), blk, 0, stream>>>(
      Wv, wT + (size_t)(H_ * D_ + KV_ * D_) * HID_, HID_, KV_ * D_);

  // fused QKV GEMM: Q f32 -> d_out, K f32 -> kbuf, V^T bf16 -> vt
  gemm_bf16<1><<<dim3(NQKV_ / TBN, BS / TBM), blk, 0, stream>>>(
      xb, wT, out, kbuf, vt, BS, NQKV_, HID_, S);

  // per-head RMSNorm + RoPE -> bf16
  rmsnorm_rope_o16<<<dim3(BS * H_ / 4),  blk, 0, stream>>>(out,  qb,   qw, cs, sn, H_);
  rmsnorm_rope_o16<<<dim3(BS * KV_ / 4), blk, 0, stream>>>(kbuf, kb16, kw, cs, sn, KV_);

  // causal MFMA flash attention (work-balanced q-tile pairs) -> bf16
  flash_bf16<<<dim3(S / 128, H_, B), blk, 0, stream>>>(qb, kb16, vt, ab16, S, S / 64);

  // Out = abuf @ Wo (f32 into d_out); Wo^T reuses wT
  transpose_bf16<<<dim3(HID_ / 32, (H_ * D_) / 32), blk, 0, stream>>>(Wo, wT, H_ * D_, HID_);
  gemm_bf16<0><<<dim3(HID_ / TBN, BS / TBM), blk, 0, stream>>>(
      ab16, wT, out, nullptr, nullptr, BS, HID_, HID_, S);
}

// Round 8
// 403.838 us; speedup vs baseline: 6.0197x; 1.0550x over previous
//
#include <hip/hip_runtime.h>
#include <hip/hip_bf16.h>
#include <math.h>

#define H_    16
#define KV_   8
#define D_    128
#define HID_  2048
#define NQKV_ 4096   // H*D + KV*D + KV*D
#define SCALE_ 0.08838834764831845f   // 128^-0.5

typedef __attribute__((ext_vector_type(8))) short bf16x8;
typedef __attribute__((ext_vector_type(4))) float f32x4;
typedef __attribute__((ext_vector_type(4))) short short4v;

__device__ inline unsigned short f2bf(float f) {
  unsigned u = __builtin_bit_cast(unsigned, f);
  u += 0x7FFF + ((u >> 16) & 1);   // RNE
  return (unsigned short)(u >> 16);
}

#define GLDS16(g, l)                                                     \
  __builtin_amdgcn_global_load_lds(                                      \
      (const __attribute__((address_space(1))) void*)(g),                \
      (__attribute__((address_space(3))) void*)(l), 16, 0, 0)

// ---------------- f32 -> bf16 (contiguous, x8 per thread) ----------------
__global__ __launch_bounds__(256) void f32_to_bf16(
    const float* __restrict__ in, unsigned short* __restrict__ out, int n8) {
  int i = blockIdx.x * 256 + threadIdx.x;
  if (i >= n8) return;
  const float4* p = (const float4*)in + (size_t)i * 2;
  float4 a = p[0], b = p[1];
  unsigned short o[8] = {f2bf(a.x), f2bf(a.y), f2bf(a.z), f2bf(a.w),
                         f2bf(b.x), f2bf(b.y), f2bf(b.z), f2bf(b.w)};
  *(bf16x8*)(out + (size_t)i * 8) = *(bf16x8*)o;
}

// ------------- f32 (K x N) -> bf16 transposed (N x K) -------------
__global__ __launch_bounds__(256) void transpose_bf16(
    const float* __restrict__ in, unsigned short* __restrict__ out, int K, int N) {
  __shared__ float t[32][33];
  const int k0 = blockIdx.y * 32, n0 = blockIdx.x * 32;
  const int r = threadIdx.x >> 3, c4 = (threadIdx.x & 7) * 4;
  float4 v = *(const float4*)(in + (size_t)(k0 + r) * N + n0 + c4);
  t[r][c4 + 0] = v.x; t[r][c4 + 1] = v.y; t[r][c4 + 2] = v.z; t[r][c4 + 3] = v.w;
  __syncthreads();
  unsigned short o[4];
#pragma unroll
  for (int j = 0; j < 4; ++j) o[j] = f2bf(t[c4 + j][r]);
  *(short4v*)(out + (size_t)(n0 + r) * K + k0 + c4) = *(short4v*)o;
}

// ------------- merged Wq/Wk/Wv transpose into concatenated (4096, 2048) -------------
__global__ __launch_bounds__(256) void transpose_qkv3(
    const float* __restrict__ Wq, const float* __restrict__ Wk,
    const float* __restrict__ Wv, unsigned short* __restrict__ out) {
  __shared__ float t[32][33];
  const int n0 = blockIdx.x * 32;   // concatenated col
  const int k0 = blockIdx.y * 32;
  const float* src; int N, nloc;
  if (n0 < H_ * D_)                  { src = Wq; N = H_ * D_;  nloc = n0; }
  else if (n0 < H_ * D_ + KV_ * D_)  { src = Wk; N = KV_ * D_; nloc = n0 - H_ * D_; }
  else                               { src = Wv; N = KV_ * D_; nloc = n0 - H_ * D_ - KV_ * D_; }
  const int r = threadIdx.x >> 3, c4 = (threadIdx.x & 7) * 4;
  float4 v = *(const float4*)(src + (size_t)(k0 + r) * N + nloc + c4);
  t[r][c4 + 0] = v.x; t[r][c4 + 1] = v.y; t[r][c4 + 2] = v.z; t[r][c4 + 3] = v.w;
  __syncthreads();
  unsigned short o[4];
#pragma unroll
  for (int j = 0; j < 4; ++j) o[j] = f2bf(t[c4 + j][r]);
  *(short4v*)(out + (size_t)(n0 + r) * HID_ + k0 + c4) = *(short4v*)o;
}

// ---------------- bf16 MFMA GEMM: C = A(M,K) @ Bt(N,K)^T ----------------
// EPI 0: C0 f32 row-major (ld = N).
// EPI 1: fused QKV epilogue: col<2048 -> Q f32 (C0, ld 2048);
//        col<3072 -> K f32 (C1, ld 1024); else V^T bf16 (C2).
#define TBM 128
#define TBN 128
#define TBK 64

template <int EPI>
__global__ __launch_bounds__(256) void gemm_bf16(
    const unsigned short* __restrict__ A,   // M x K row-major
    const unsigned short* __restrict__ Bt,  // N x K row-major
    float* __restrict__ C0, float* __restrict__ C1,
    unsigned short* __restrict__ C2, int M, int N, int K, int S) {
  __shared__ unsigned short As[TBM * TBK];  // [m][k], 16 KB
  __shared__ unsigned short Bs[TBN * TBK];  // [n][k], 16 KB
  const int tid = threadIdx.x;
  const int w = tid >> 6, lane = tid & 63;
  const int wm = w >> 1, wn = w & 1;
  const int fr = lane & 15, fq = lane >> 4;
  const int row0 = blockIdx.y * TBM, col0 = blockIdx.x * TBN;

  const unsigned short* Ab = A + (size_t)row0 * K;
  const unsigned short* Bb = Bt + (size_t)col0 * K;
  const int sm = lane >> 3;         // row within 8-row segment
  const int sk = (lane & 7) * 8;    // k offset (8 elems = 16B)

  f32x4 acc[4][4] = {};

  for (int k0 = 0; k0 < K; k0 += TBK) {
    __syncthreads();
#pragma unroll
    for (int p = 0; p < 4; ++p) {
      const int seg = w * 4 + p;            // 0..15, wave-uniform
      const int m = seg * 8 + sm;
      GLDS16(Ab + (size_t)m * K + k0 + sk, As + seg * 512);
      GLDS16(Bb + (size_t)m * K + k0 + sk, Bs + seg * 512);
    }
    __syncthreads();
#pragma unroll
    for (int s = 0; s < 2; ++s) {
      bf16x8 af[4], bfr[4];
#pragma unroll
      for (int i = 0; i < 4; ++i)
        af[i] = *(const bf16x8*)(As + (wm * 64 + i * 16 + fr) * TBK + s * 32 + fq * 8);
#pragma unroll
      for (int j = 0; j < 4; ++j)
        bfr[j] = *(const bf16x8*)(Bs + (wn * 64 + j * 16 + fr) * TBK + s * 32 + fq * 8);
#pragma unroll
      for (int i = 0; i < 4; ++i)
#pragma unroll
        for (int j = 0; j < 4; ++j)
          acc[i][j] = __builtin_amdgcn_mfma_f32_16x16x32_bf16(af[i], bfr[j], acc[i][j], 0, 0, 0);
    }
  }

  // C/D layout (m89-verified): col = lane&15, row = (lane>>4)*4 + reg
  if constexpr (EPI == 0) {
#pragma unroll
    for (int i = 0; i < 4; ++i)
#pragma unroll
      for (int j = 0; j < 4; ++j) {
        const int col = col0 + wn * 64 + j * 16 + fr;
#pragma unroll
        for (int r = 0; r < 4; ++r) {
          const int row = row0 + wm * 64 + i * 16 + fq * 4 + r;
          C0[(size_t)row * N + col] = acc[i][j][r];
        }
      }
  } else {  // fused QKV
    if (col0 < H_ * D_) {  // Q: f32 row-major, ld = 2048
#pragma unroll
      for (int i = 0; i < 4; ++i)
#pragma unroll
        for (int j = 0; j < 4; ++j) {
          const int col = col0 + wn * 64 + j * 16 + fr;
#pragma unroll
          for (int r = 0; r < 4; ++r) {
            const int row = row0 + wm * 64 + i * 16 + fq * 4 + r;
            C0[(size_t)row * (H_ * D_) + col] = acc[i][j][r];
          }
        }
    } else if (col0 < H_ * D_ + KV_ * D_) {  // K: f32 row-major, ld = 1024
#pragma unroll
      for (int i = 0; i < 4; ++i)
#pragma unroll
        for (int j = 0; j < 4; ++j) {
          const int col = col0 - H_ * D_ + wn * 64 + j * 16 + fr;
#pragma unroll
          for (int r = 0; r < 4; ++r) {
            const int row = row0 + wm * 64 + i * 16 + fq * 4 + r;
            C1[(size_t)row * (KV_ * D_) + col] = acc[i][j][r];
          }
        }
    } else {  // V^T bf16: [b*KV+kvh][d][s]
#pragma unroll
      for (int i = 0; i < 4; ++i)
#pragma unroll
        for (int j = 0; j < 4; ++j) {
          const int cc = col0 - (H_ * D_ + KV_ * D_) + wn * 64 + j * 16 + fr;
          const int kvh = cc >> 7, d = cc & 127;
          const int row = row0 + wm * 64 + i * 16 + fq * 4;   // 4 consecutive s
          const int b = row / S, s = row - b * S;
          unsigned short o[4] = {f2bf(acc[i][j][0]), f2bf(acc[i][j][1]),
                                 f2bf(acc[i][j][2]), f2bf(acc[i][j][3])};
          *(short4v*)(C2 + ((size_t)(b * KV_ + kvh) * D_ + d) * S + s) = *(short4v*)o;
        }
    }
  }
}

// ------- fused per-head RMSNorm + RoPE: f32 in, bf16 out (oscale folds SCALE into Q) -------
__global__ __launch_bounds__(256) void rmsnorm_rope_o16(
    const float* __restrict__ p, unsigned short* __restrict__ o16,
    const float* __restrict__ w, const float* __restrict__ cs,
    const float* __restrict__ sn, int nheads, float oscale) {
  const int row  = blockIdx.x * 4 + (threadIdx.x >> 6);
  const int lane = threadIdx.x & 63;
  const float* base = p + (size_t)row * D_;
  float x1 = base[lane];
  float x2 = base[lane + 64];
  float ss = x1 * x1 + x2 * x2;
#pragma unroll
  for (int m = 32; m; m >>= 1) ss += __shfl_xor(ss, m);
  float r = rsqrtf(ss * (1.0f / 128.0f) + 1e-6f);
  const size_t sidx = (size_t)(row / nheads) * D_;
  float n1 = x1 * r * w[lane];
  float n2 = x2 * r * w[lane + 64];
  unsigned short* ob = o16 + (size_t)row * D_;
  ob[lane]      = f2bf((n1 * cs[sidx + lane]      - n2 * sn[sidx + lane])      * oscale);
  ob[lane + 64] = f2bf((n2 * cs[sidx + lane + 64] + n1 * sn[sidx + lane + 64]) * oscale);
}

// ------------- bf16 MFMA causal flash attention, GQA, KVBLK=128, work-balanced -------------
// Each block processes q-tiles {bid, nqt-1-bid}: uniform staging (17 KV-tiles), no tail.
// Qb: (B*S, H, D) bf16 (Q pre-scaled by SCALE_); Kb: (B*S, KV, D); Vt: (B*KV, D, S); O bf16.
__global__ __launch_bounds__(256) void flash_bf16(
    const unsigned short* __restrict__ Qb, const unsigned short* __restrict__ Kb,
    const unsigned short* __restrict__ Vt, unsigned short* __restrict__ O,
    int S, int nqt) {
  __shared__ unsigned short Kt[128 * 128];    // [kv][d], chunk-swizzled, 32 KB
  __shared__ unsigned short Vs[128 * 128];    // [d][kv], chunk-swizzled, 32 KB
  __shared__ unsigned short Pl[4][16 * 128];  // per-wave P [q][kv], swizzled, 4 KB each
  const int h = blockIdx.y, b = blockIdx.z;
  const int kvh = h >> 1;                     // groups = H/KV = 2
  const int tid = threadIdx.x, w = tid >> 6, lane = tid & 63;
  const int fr = lane & 15, fq = lane >> 4;
  const int rl = lane >> 4;                   // staging row-within-4
  const int sch = lane & 15;                  // staging chunk 0..15
  const unsigned short* vhead = Vt + (size_t)(b * KV_ + kvh) * D_ * S;

#pragma unroll 1
  for (int half = 0; half < 2; ++half) {
    const int qt = half ? (nqt - 1 - (int)blockIdx.x) : (int)blockIdx.x;
    const int q0 = qt * 64;
    const int nkt = (q0 + 64 + 127) >> 7;     // KV-tiles of 128 covering kv <= q0+63

    // Q A-fragments in registers: rows = fr (wave-local), 4 k-steps of 32
    bf16x8 qf[4];
    {
      const unsigned short* qp =
          Qb + ((size_t)(b * S + q0 + w * 16 + fr) * H_ + h) * D_;
#pragma unroll
      for (int s = 0; s < 4; ++s) qf[s] = *(const bf16x8*)(qp + s * 32 + fq * 8);
    }

    f32x4 acco[8] = {};   // O[q=fq*4+r][d=16c+fr]
    float mrow[4] = {-1e30f, -1e30f, -1e30f, -1e30f};
    float lrow[4] = {0.f, 0.f, 0.f, 0.f};

#pragma unroll 1
    for (int kt = 0; kt < nkt; ++kt) {
      __syncthreads();   // prev tile's (or prev half's) LDS reads done
      // ---- stage K [128][128] and V^T [128][128], pre-swizzled global source ----
#pragma unroll
      for (int p = 0; p < 8; ++p) {
        const int r = p * 16 + w * 4 + rl;            // row 0..127, wave-uniform base
        const int gch = (sch & 8) | ((sch ^ r) & 7);  // source chunk permutation
        GLDS16(Kb + ((size_t)(b * S + kt * 128 + r) * KV_ + kvh) * D_ + gch * 8,
               Kt + (p * 16 + w * 4) * 128);
        GLDS16(vhead + (size_t)r * S + kt * 128 + gch * 8,
               Vs + (p * 16 + w * 4) * 128);
      }
      __syncthreads();   // vmcnt drained by compiler before barrier

      // ---- S = Q @ K^T  (C: row=q=fq*4+r, col=kv=16t+fr); Q pre-scaled ----
      f32x4 sa[8];
      __builtin_amdgcn_s_setprio(1);
#pragma unroll
      for (int t = 0; t < 8; ++t) {
        f32x4 a = {};
        const int kv = 16 * t + fr;
#pragma unroll
        for (int s = 0; s < 4; ++s) {
          const int ch = 4 * s + fq;
          const int chs = (ch & 8) | ((ch ^ kv) & 7);
          bf16x8 kf = *(const bf16x8*)(Kt + kv * 128 + chs * 8);
          a = __builtin_amdgcn_mfma_f32_16x16x32_bf16(qf[s], kf, a, 0, 0, 0);
        }
        sa[t] = a;
      }
      __builtin_amdgcn_s_setprio(0);

      // causal mask on the last tile (global indices)
      if (kt == nkt - 1) {
#pragma unroll
        for (int t = 0; t < 8; ++t) {
          const int kvg = kt * 128 + 16 * t + fr;
#pragma unroll
          for (int r = 0; r < 4; ++r)
            if (kvg > q0 + w * 16 + fq * 4 + r) sa[t][r] = -1e30f;
        }
      }

      // ---- online softmax (rows owned per reg r; reduce across fr lanes) ----
      float al[4];
#pragma unroll
      for (int r = 0; r < 4; ++r) {
        float mx = sa[0][r];
#pragma unroll
        for (int t = 1; t < 8; ++t) mx = fmaxf(mx, sa[t][r]);
        mx = fmaxf(mx, __shfl_xor(mx, 1));
        mx = fmaxf(mx, __shfl_xor(mx, 2));
        mx = fmaxf(mx, __shfl_xor(mx, 4));
        mx = fmaxf(mx, __shfl_xor(mx, 8));
        const float mn = fmaxf(mrow[r], mx);
        al[r] = __expf(mrow[r] - mn);
        mrow[r] = mn;
        float sum = 0.f;
#pragma unroll
        for (int t = 0; t < 8; ++t) {
          const float pv = __expf(sa[t][r] - mn);
          sa[t][r] = pv;
          sum += pv;
        }
        sum += __shfl_xor(sum, 1);
        sum += __shfl_xor(sum, 2);
        sum += __shfl_xor(sum, 4);
        sum += __shfl_xor(sum, 8);
        lrow[r] = lrow[r] * al[r] + sum;
#pragma unroll
        for (int c = 0; c < 8; ++c) acco[c][r] *= al[r];
      }

      // ---- P -> per-wave LDS (bf16, chunk-swizzled) ----
      unsigned short* pw = &Pl[w][0];
#pragma unroll
      for (int t = 0; t < 8; ++t) {
        const int kv = 16 * t + fr;
        const int ch = kv >> 3;
#pragma unroll
        for (int r = 0; r < 4; ++r) {
          const int q = fq * 4 + r;
          pw[q * 128 + ((ch & 8) | ((ch ^ q) & 7)) * 8 + (kv & 7)] = f2bf(sa[t][r]);
        }
      }

      // ---- O += P @ V  (A = P[q=fr][kv], B = V^T rows) ----
      bf16x8 pf[4];
#pragma unroll
      for (int s = 0; s < 4; ++s) {
        const int ch = 4 * s + fq;
        pf[s] = *(const bf16x8*)(pw + fr * 128 + ((ch & 8) | ((ch ^ fr) & 7)) * 8);
      }
      __builtin_amdgcn_s_setprio(1);
#pragma unroll
      for (int c = 0; c < 8; ++c) {
        const int d = 16 * c + fr;
#pragma unroll
        for (int s = 0; s < 4; ++s) {
          const int ch = 4 * s + fq;
          bf16x8 vf = *(const bf16x8*)(Vs + d * 128 + ((ch & 8) | ((ch ^ d) & 7)) * 8);
          acco[c] = __builtin_amdgcn_mfma_f32_16x16x32_bf16(pf[s], vf, acco[c], 0, 0, 0);
        }
      }
      __builtin_amdgcn_s_setprio(0);
    }

    // ---- epilogue: O = acc / l, bf16 ----
    float inv[4];
#pragma unroll
    for (int r = 0; r < 4; ++r) inv[r] = 1.0f / lrow[r];
#pragma unroll
    for (int c = 0; c < 8; ++c) {
#pragma unroll
      for (int r = 0; r < 4; ++r) {
        const int q = q0 + w * 16 + fq * 4 + r;
        O[(size_t)(b * S + q) * (H_ * D_) + h * D_ + 16 * c + fr] =
            f2bf(acco[c][r] * inv[r]);
      }
    }
  }
}

extern "C" void kernel_launch(void* const* d_in, const int* in_sizes, int n_in,
                              void* d_out, int out_size, void* d_ws, size_t ws_size,
                              hipStream_t stream) {
  const float* x  = (const float*)d_in[0];
  const float* sn = (const float*)d_in[1];   // sin
  const float* cs = (const float*)d_in[2];   // cos
  // d_in[3] = attention_mask: causal, applied analytically -> unused
  const float* Wq = (const float*)d_in[4];
  const float* Wk = (const float*)d_in[5];
  const float* Wv = (const float*)d_in[6];
  const float* Wo = (const float*)d_in[7];
  const float* qw = (const float*)d_in[8];
  const float* kw = (const float*)d_in[9];
  float* out = (float*)d_out;

  const int BS = in_sizes[0] / HID_;   // B*S = 4096
  const int S  = in_sizes[3] / BS;     // 2048
  const int B  = BS / S;

  // workspace layout (80 MB total)
  float* kbuf = (float*)d_ws;                                  // BS*KV*D f32  16 MB
  unsigned short* vt   = (unsigned short*)(kbuf + (size_t)BS * KV_ * D_);  // 8 MB
  unsigned short* xb   = vt + (size_t)BS * KV_ * D_;           // BS*HID bf16  16 MB
  unsigned short* wT   = xb + (size_t)BS * HID_;               // 4096*2048 bf16 16 MB
  unsigned short* qb   = wT + (size_t)NQKV_ * HID_;            // BS*H*D bf16  16 MB
  unsigned short* kb16 = qb + (size_t)BS * H_ * D_;            // BS*KV*D bf16  8 MB
  unsigned short* ab16 = xb;                                   // reuse xb after QKV GEMM

  dim3 blk(256);
  const int n8x = BS * HID_ / 8;

  // x -> bf16
  f32_to_bf16<<<dim3(n8x / 256), blk, 0, stream>>>(x, xb, n8x);

  // transpose all three weights into one concatenated (N=4096, K=2048) buffer
  transpose_qkv3<<<dim3(NQKV_ / 32, HID_ / 32), blk, 0, stream>>>(Wq, Wk, Wv, wT);

  // fused QKV GEMM: Q f32 -> d_out, K f32 -> kbuf, V^T bf16 -> vt
  gemm_bf16<1><<<dim3(NQKV_ / TBN, BS / TBM), blk, 0, stream>>>(
      xb, wT, out, kbuf, vt, BS, NQKV_, HID_, S);

  // per-head RMSNorm + RoPE -> bf16 (SCALE folded into Q)
  rmsnorm_rope_o16<<<dim3(BS * H_ / 4),  blk, 0, stream>>>(out,  qb,   qw, cs, sn, H_,  SCALE_);
  rmsnorm_rope_o16<<<dim3(BS * KV_ / 4), blk, 0, stream>>>(kbuf, kb16, kw, cs, sn, KV_, 1.0f);

  // causal MFMA flash attention (KVBLK=128, work-balanced q-tile pairs) -> bf16
  flash_bf16<<<dim3(S / 128, H_, B), blk, 0, stream>>>(qb, kb16, vt, ab16, S, S / 64);

  // Out = abuf @ Wo (f32 into d_out); Wo^T reuses wT
  transpose_bf16<<<dim3(HID_ / 32, (H_ * D_) / 32), blk, 0, stream>>>(Wo, wT, H_ * D_, HID_);
  gemm_bf16<0><<<dim3(HID_ / TBN, BS / TBM), blk, 0, stream>>>(
      ab16, wT, out, nullptr, nullptr, BS, HID_, HID_, S);
}

// Round 9
// 398.870 us; speedup vs baseline: 6.0946x; 1.0125x over previous
//
#include <hip/hip_runtime.h>
#include <hip/hip_bf16.h>
#include <math.h>

#define H_    16
#define KV_   8
#define D_    128
#define HID_  2048
#define NQKV_ 4096   // H*D + KV*D + KV*D
#define SCALE_ 0.08838834764831845f   // 128^-0.5

typedef __attribute__((ext_vector_type(8))) short bf16x8;
typedef __attribute__((ext_vector_type(4))) float f32x4;
typedef __attribute__((ext_vector_type(4))) short short4v;

__device__ inline unsigned short f2bf(float f) {
  unsigned u = __builtin_bit_cast(unsigned, f);
  u += 0x7FFF + ((u >> 16) & 1);   // RNE
  return (unsigned short)(u >> 16);
}

#define GLDS16(g, l)                                                     \
  __builtin_amdgcn_global_load_lds(                                      \
      (const __attribute__((address_space(1))) void*)(g),                \
      (__attribute__((address_space(3))) void*)(l), 16, 0, 0)

// ---------------- f32 -> bf16 (contiguous, x8 per thread) ----------------
__global__ __launch_bounds__(256) void f32_to_bf16(
    const float* __restrict__ in, unsigned short* __restrict__ out, int n8) {
  int i = blockIdx.x * 256 + threadIdx.x;
  if (i >= n8) return;
  const float4* p = (const float4*)in + (size_t)i * 2;
  float4 a = p[0], b = p[1];
  unsigned short o[8] = {f2bf(a.x), f2bf(a.y), f2bf(a.z), f2bf(a.w),
                         f2bf(b.x), f2bf(b.y), f2bf(b.z), f2bf(b.w)};
  *(bf16x8*)(out + (size_t)i * 8) = *(bf16x8*)o;
}

// ------------- f32 (K x N) -> bf16 transposed (N x K) -------------
__global__ __launch_bounds__(256) void transpose_bf16(
    const float* __restrict__ in, unsigned short* __restrict__ out, int K, int N) {
  __shared__ float t[32][33];
  const int k0 = blockIdx.y * 32, n0 = blockIdx.x * 32;
  const int r = threadIdx.x >> 3, c4 = (threadIdx.x & 7) * 4;
  float4 v = *(const float4*)(in + (size_t)(k0 + r) * N + n0 + c4);
  t[r][c4 + 0] = v.x; t[r][c4 + 1] = v.y; t[r][c4 + 2] = v.z; t[r][c4 + 3] = v.w;
  __syncthreads();
  unsigned short o[4];
#pragma unroll
  for (int j = 0; j < 4; ++j) o[j] = f2bf(t[c4 + j][r]);
  *(short4v*)(out + (size_t)(n0 + r) * K + k0 + c4) = *(short4v*)o;
}

// ------------- merged Wq/Wk/Wv transpose into concatenated (4096, 2048) -------------
__global__ __launch_bounds__(256) void transpose_qkv3(
    const float* __restrict__ Wq, const float* __restrict__ Wk,
    const float* __restrict__ Wv, unsigned short* __restrict__ out) {
  __shared__ float t[32][33];
  const int n0 = blockIdx.x * 32;   // concatenated col
  const int k0 = blockIdx.y * 32;
  const float* src; int N, nloc;
  if (n0 < H_ * D_)                  { src = Wq; N = H_ * D_;  nloc = n0; }
  else if (n0 < H_ * D_ + KV_ * D_)  { src = Wk; N = KV_ * D_; nloc = n0 - H_ * D_; }
  else                               { src = Wv; N = KV_ * D_; nloc = n0 - H_ * D_ - KV_ * D_; }
  const int r = threadIdx.x >> 3, c4 = (threadIdx.x & 7) * 4;
  float4 v = *(const float4*)(src + (size_t)(k0 + r) * N + nloc + c4);
  t[r][c4 + 0] = v.x; t[r][c4 + 1] = v.y; t[r][c4 + 2] = v.z; t[r][c4 + 3] = v.w;
  __syncthreads();
  unsigned short o[4];
#pragma unroll
  for (int j = 0; j < 4; ++j) o[j] = f2bf(t[c4 + j][r]);
  *(short4v*)(out + (size_t)(n0 + r) * HID_ + k0 + c4) = *(short4v*)o;
}

// ======== 256x256x64 bf16 MFMA GEMM, 8 waves, LDS double-buffer, counted vmcnt ========
// C = A(M,K) @ Bt(N,K)^T.
// EPI 0: C0 f32 row-major (ld = N).
// EPI 1: fused QKV epilogue: col<2048 -> Q f32 (C0, ld 2048);
//        col<3072 -> K f32 (C1, ld 1024); else V^T bf16 (C2: [b*KV+kvh][d][s]).
// LDS swizzle: row r's 8 16B-chunks stored at slot = chunk ^ (r&7) (involution);
// staged via pre-swizzled GLOBAL source (linear gload_lds dest), read back with same XOR.
#define QBM 256
#define QBN 256
#define QBK 64

template <int EPI>
__global__ __launch_bounds__(512, 2) void gemm256(
    const unsigned short* __restrict__ A,   // M x K row-major
    const unsigned short* __restrict__ Bt,  // N x K row-major
    float* __restrict__ C0, float* __restrict__ C1,
    unsigned short* __restrict__ C2, int M, int N, int K, int S) {
  __shared__ unsigned short As[2][QBM * QBK];  // 32 KB each
  __shared__ unsigned short Bs[2][QBN * QBK];  // 32 KB each  (total 128 KB)
  const int tid = threadIdx.x;
  const int w = tid >> 6, lane = tid & 63;
  const int wm = w >> 2, wn = w & 3;           // 2 x 4 wave grid
  const int fr = lane & 15, fq = lane >> 4;
  const int row0 = blockIdx.y * QBM, col0 = blockIdx.x * QBN;

  const unsigned short* Ab = A + (size_t)row0 * K;
  const unsigned short* Bb = Bt + (size_t)col0 * K;
  // staging map: instr p (0..3): wave w covers rows p*64 + w*8 .. +7;
  // lane l -> row (l>>3), chunk slot (l&7); source chunk = slot ^ (row&7).
  const int srow = w * 8 + (lane >> 3);
  const int sc   = lane & 7;
  const int nt   = K / QBK;

  f32x4 acc[8][4] = {};

#define STAGE256(t_, buf_)                                                      \
  {                                                                             \
    const int k0_ = (t_) * QBK;                                                 \
    _Pragma("unroll")                                                           \
    for (int p = 0; p < 4; ++p) {                                               \
      const int r_ = p * 64 + srow;                                             \
      const int gc_ = sc ^ (r_ & 7);                                            \
      GLDS16(Ab + (size_t)r_ * K + k0_ + gc_ * 8,                               \
             &As[buf_][(p * 64 + w * 8) * QBK]);                                \
      GLDS16(Bb + (size_t)r_ * K + k0_ + gc_ * 8,                               \
             &Bs[buf_][(p * 64 + w * 8) * QBK]);                                \
    }                                                                           \
  }

  STAGE256(0, 0);
  STAGE256(1, 1);
  asm volatile("s_waitcnt vmcnt(8)" ::: "memory");   // tile 0 resident
  __builtin_amdgcn_s_barrier();
  __builtin_amdgcn_sched_barrier(0);

  for (int t = 0; t < nt; ++t) {
    const int buf = t & 1;
    // ---- compute tile t from buf (tile t+1 loads remain in flight) ----
    __builtin_amdgcn_s_setprio(1);
#pragma unroll
    for (int s = 0; s < 2; ++s) {
      bf16x8 af[8], bf[4];
#pragma unroll
      for (int i = 0; i < 8; ++i) {
        const int r = wm * 128 + i * 16 + fr;
        af[i] = *(const bf16x8*)(&As[buf][r * QBK + (((s << 2) | fq) ^ (r & 7)) * 8]);
      }
#pragma unroll
      for (int j = 0; j < 4; ++j) {
        const int r = wn * 64 + j * 16 + fr;
        bf[j] = *(const bf16x8*)(&Bs[buf][r * QBK + (((s << 2) | fq) ^ (r & 7)) * 8]);
      }
#pragma unroll
      for (int i = 0; i < 8; ++i)
#pragma unroll
        for (int j = 0; j < 4; ++j)
          acc[i][j] = __builtin_amdgcn_mfma_f32_16x16x32_bf16(af[i], bf[j], acc[i][j], 0, 0, 0);
    }
    __builtin_amdgcn_s_setprio(0);
    __builtin_amdgcn_sched_barrier(0);
    __builtin_amdgcn_s_barrier();            // all waves done reading buf
    if (t + 2 < nt) {
      STAGE256(t + 2, buf);                  // overwrite buf with tile t+2
      asm volatile("s_waitcnt vmcnt(8)" ::: "memory");  // tile t+1 resident
    } else {
      asm volatile("s_waitcnt vmcnt(0)" ::: "memory");  // drain (also pre-exit safety)
    }
    __builtin_amdgcn_s_barrier();            // publish tile t+1
    __builtin_amdgcn_sched_barrier(0);
  }

  // ---- epilogue: C/D layout col = lane&15, row = (lane>>4)*4 + reg ----
  if constexpr (EPI == 0) {
#pragma unroll
    for (int i = 0; i < 8; ++i)
#pragma unroll
      for (int j = 0; j < 4; ++j) {
        const int col = col0 + wn * 64 + j * 16 + fr;
#pragma unroll
        for (int r = 0; r < 4; ++r) {
          const int row = row0 + wm * 128 + i * 16 + fq * 4 + r;
          C0[(size_t)row * N + col] = acc[i][j][r];
        }
      }
  } else {  // fused QKV: per-block uniform section (256-col tiles align to 2048/3072)
    if (col0 < H_ * D_) {  // Q: f32, ld 2048
#pragma unroll
      for (int i = 0; i < 8; ++i)
#pragma unroll
        for (int j = 0; j < 4; ++j) {
          const int col = col0 + wn * 64 + j * 16 + fr;
#pragma unroll
          for (int r = 0; r < 4; ++r) {
            const int row = row0 + wm * 128 + i * 16 + fq * 4 + r;
            C0[(size_t)row * (H_ * D_) + col] = acc[i][j][r];
          }
        }
    } else if (col0 < H_ * D_ + KV_ * D_) {  // K: f32, ld 1024
#pragma unroll
      for (int i = 0; i < 8; ++i)
#pragma unroll
        for (int j = 0; j < 4; ++j) {
          const int col = col0 - H_ * D_ + wn * 64 + j * 16 + fr;
#pragma unroll
          for (int r = 0; r < 4; ++r) {
            const int row = row0 + wm * 128 + i * 16 + fq * 4 + r;
            C1[(size_t)row * (KV_ * D_) + col] = acc[i][j][r];
          }
        }
    } else {  // V^T bf16: [b*KV+kvh][d][s]
#pragma unroll
      for (int i = 0; i < 8; ++i)
#pragma unroll
        for (int j = 0; j < 4; ++j) {
          const int cc = col0 - (H_ * D_ + KV_ * D_) + wn * 64 + j * 16 + fr;
          const int kvh = cc >> 7, d = cc & 127;
          const int row = row0 + wm * 128 + i * 16 + fq * 4;   // 4 consecutive s
          const int b = row / S, s = row - b * S;
          unsigned short o[4] = {f2bf(acc[i][j][0]), f2bf(acc[i][j][1]),
                                 f2bf(acc[i][j][2]), f2bf(acc[i][j][3])};
          *(short4v*)(C2 + ((size_t)(b * KV_ + kvh) * D_ + d) * S + s) = *(short4v*)o;
        }
    }
  }
#undef STAGE256
}

// ------- fused per-head RMSNorm + RoPE: f32 in, bf16 out (oscale folds SCALE into Q) -------
__global__ __launch_bounds__(256) void rmsnorm_rope_o16(
    const float* __restrict__ p, unsigned short* __restrict__ o16,
    const float* __restrict__ w, const float* __restrict__ cs,
    const float* __restrict__ sn, int nheads, float oscale) {
  const int row  = blockIdx.x * 4 + (threadIdx.x >> 6);
  const int lane = threadIdx.x & 63;
  const float* base = p + (size_t)row * D_;
  float x1 = base[lane];
  float x2 = base[lane + 64];
  float ss = x1 * x1 + x2 * x2;
#pragma unroll
  for (int m = 32; m; m >>= 1) ss += __shfl_xor(ss, m);
  float r = rsqrtf(ss * (1.0f / 128.0f) + 1e-6f);
  const size_t sidx = (size_t)(row / nheads) * D_;
  float n1 = x1 * r * w[lane];
  float n2 = x2 * r * w[lane + 64];
  unsigned short* ob = o16 + (size_t)row * D_;
  ob[lane]      = f2bf((n1 * cs[sidx + lane]      - n2 * sn[sidx + lane])      * oscale);
  ob[lane + 64] = f2bf((n2 * cs[sidx + lane + 64] + n1 * sn[sidx + lane + 64]) * oscale);
}

// ------------- bf16 MFMA causal flash attention, GQA, KVBLK=128, work-balanced -------------
__global__ __launch_bounds__(256) void flash_bf16(
    const unsigned short* __restrict__ Qb, const unsigned short* __restrict__ Kb,
    const unsigned short* __restrict__ Vt, unsigned short* __restrict__ O,
    int S, int nqt) {
  __shared__ unsigned short Kt[128 * 128];    // [kv][d], chunk-swizzled, 32 KB
  __shared__ unsigned short Vs[128 * 128];    // [d][kv], chunk-swizzled, 32 KB
  __shared__ unsigned short Pl[4][16 * 128];  // per-wave P [q][kv], swizzled, 4 KB each
  const int h = blockIdx.y, b = blockIdx.z;
  const int kvh = h >> 1;                     // groups = H/KV = 2
  const int tid = threadIdx.x, w = tid >> 6, lane = tid & 63;
  const int fr = lane & 15, fq = lane >> 4;
  const int rl = lane >> 4;                   // staging row-within-4
  const int sch = lane & 15;                  // staging chunk 0..15
  const unsigned short* vhead = Vt + (size_t)(b * KV_ + kvh) * D_ * S;

#pragma unroll 1
  for (int half = 0; half < 2; ++half) {
    const int qt = half ? (nqt - 1 - (int)blockIdx.x) : (int)blockIdx.x;
    const int q0 = qt * 64;
    const int nkt = (q0 + 64 + 127) >> 7;     // KV-tiles of 128 covering kv <= q0+63

    bf16x8 qf[4];
    {
      const unsigned short* qp =
          Qb + ((size_t)(b * S + q0 + w * 16 + fr) * H_ + h) * D_;
#pragma unroll
      for (int s = 0; s < 4; ++s) qf[s] = *(const bf16x8*)(qp + s * 32 + fq * 8);
    }

    f32x4 acco[8] = {};   // O[q=fq*4+r][d=16c+fr]
    float mrow[4] = {-1e30f, -1e30f, -1e30f, -1e30f};
    float lrow[4] = {0.f, 0.f, 0.f, 0.f};

#pragma unroll 1
    for (int kt = 0; kt < nkt; ++kt) {
      __syncthreads();
#pragma unroll
      for (int p = 0; p < 8; ++p) {
        const int r = p * 16 + w * 4 + rl;
        const int gch = (sch & 8) | ((sch ^ r) & 7);
        GLDS16(Kb + ((size_t)(b * S + kt * 128 + r) * KV_ + kvh) * D_ + gch * 8,
               Kt + (p * 16 + w * 4) * 128);
        GLDS16(vhead + (size_t)r * S + kt * 128 + gch * 8,
               Vs + (p * 16 + w * 4) * 128);
      }
      __syncthreads();

      f32x4 sa[8];
      __builtin_amdgcn_s_setprio(1);
#pragma unroll
      for (int t = 0; t < 8; ++t) {
        f32x4 a = {};
        const int kv = 16 * t + fr;
#pragma unroll
        for (int s = 0; s < 4; ++s) {
          const int ch = 4 * s + fq;
          const int chs = (ch & 8) | ((ch ^ kv) & 7);
          bf16x8 kf = *(const bf16x8*)(Kt + kv * 128 + chs * 8);
          a = __builtin_amdgcn_mfma_f32_16x16x32_bf16(qf[s], kf, a, 0, 0, 0);
        }
        sa[t] = a;
      }
      __builtin_amdgcn_s_setprio(0);

      if (kt == nkt - 1) {
#pragma unroll
        for (int t = 0; t < 8; ++t) {
          const int kvg = kt * 128 + 16 * t + fr;
#pragma unroll
          for (int r = 0; r < 4; ++r)
            if (kvg > q0 + w * 16 + fq * 4 + r) sa[t][r] = -1e30f;
        }
      }

      float al[4];
#pragma unroll
      for (int r = 0; r < 4; ++r) {
        float mx = sa[0][r];
#pragma unroll
        for (int t = 1; t < 8; ++t) mx = fmaxf(mx, sa[t][r]);
        mx = fmaxf(mx, __shfl_xor(mx, 1));
        mx = fmaxf(mx, __shfl_xor(mx, 2));
        mx = fmaxf(mx, __shfl_xor(mx, 4));
        mx = fmaxf(mx, __shfl_xor(mx, 8));
        const float mn = fmaxf(mrow[r], mx);
        al[r] = __expf(mrow[r] - mn);
        mrow[r] = mn;
        float sum = 0.f;
#pragma unroll
        for (int t = 0; t < 8; ++t) {
          const float pv = __expf(sa[t][r] - mn);
          sa[t][r] = pv;
          sum += pv;
        }
        sum += __shfl_xor(sum, 1);
        sum += __shfl_xor(sum, 2);
        sum += __shfl_xor(sum, 4);
        sum += __shfl_xor(sum, 8);
        lrow[r] = lrow[r] * al[r] + sum;
#pragma unroll
        for (int c = 0; c < 8; ++c) acco[c][r] *= al[r];
      }

      unsigned short* pw = &Pl[w][0];
#pragma unroll
      for (int t = 0; t < 8; ++t) {
        const int kv = 16 * t + fr;
        const int ch = kv >> 3;
#pragma unroll
        for (int r = 0; r < 4; ++r) {
          const int q = fq * 4 + r;
          pw[q * 128 + ((ch & 8) | ((ch ^ q) & 7)) * 8 + (kv & 7)] = f2bf(sa[t][r]);
        }
      }

      bf16x8 pf[4];
#pragma unroll
      for (int s = 0; s < 4; ++s) {
        const int ch = 4 * s + fq;
        pf[s] = *(const bf16x8*)(pw + fr * 128 + ((ch & 8) | ((ch ^ fr) & 7)) * 8);
      }
      __builtin_amdgcn_s_setprio(1);
#pragma unroll
      for (int c = 0; c < 8; ++c) {
        const int d = 16 * c + fr;
#pragma unroll
        for (int s = 0; s < 4; ++s) {
          const int ch = 4 * s + fq;
          bf16x8 vf = *(const bf16x8*)(Vs + d * 128 + ((ch & 8) | ((ch ^ d) & 7)) * 8);
          acco[c] = __builtin_amdgcn_mfma_f32_16x16x32_bf16(pf[s], vf, acco[c], 0, 0, 0);
        }
      }
      __builtin_amdgcn_s_setprio(0);
    }

    float inv[4];
#pragma unroll
    for (int r = 0; r < 4; ++r) inv[r] = 1.0f / lrow[r];
#pragma unroll
    for (int c = 0; c < 8; ++c) {
#pragma unroll
      for (int r = 0; r < 4; ++r) {
        const int q = q0 + w * 16 + fq * 4 + r;
        O[(size_t)(b * S + q) * (H_ * D_) + h * D_ + 16 * c + fr] =
            f2bf(acco[c][r] * inv[r]);
      }
    }
  }
}

extern "C" void kernel_launch(void* const* d_in, const int* in_sizes, int n_in,
                              void* d_out, int out_size, void* d_ws, size_t ws_size,
                              hipStream_t stream) {
  const float* x  = (const float*)d_in[0];
  const float* sn = (const float*)d_in[1];   // sin
  const float* cs = (const float*)d_in[2];   // cos
  // d_in[3] = attention_mask: causal, applied analytically -> unused
  const float* Wq = (const float*)d_in[4];
  const float* Wk = (const float*)d_in[5];
  const float* Wv = (const float*)d_in[6];
  const float* Wo = (const float*)d_in[7];
  const float* qw = (const float*)d_in[8];
  const float* kw = (const float*)d_in[9];
  float* out = (float*)d_out;

  const int BS = in_sizes[0] / HID_;   // B*S = 4096
  const int S  = in_sizes[3] / BS;     // 2048
  const int B  = BS / S;

  // workspace layout (80 MB total)
  float* kbuf = (float*)d_ws;                                  // BS*KV*D f32  16 MB
  unsigned short* vt   = (unsigned short*)(kbuf + (size_t)BS * KV_ * D_);  // 8 MB
  unsigned short* xb   = vt + (size_t)BS * KV_ * D_;           // BS*HID bf16  16 MB
  unsigned short* wT   = xb + (size_t)BS * HID_;               // 4096*2048 bf16 16 MB
  unsigned short* qb   = wT + (size_t)NQKV_ * HID_;            // BS*H*D bf16  16 MB
  unsigned short* kb16 = qb + (size_t)BS * H_ * D_;            // BS*KV*D bf16  8 MB
  unsigned short* ab16 = xb;                                   // reuse xb after QKV GEMM

  dim3 blk(256);
  const int n8x = BS * HID_ / 8;

  // x -> bf16
  f32_to_bf16<<<dim3(n8x / 256), blk, 0, stream>>>(x, xb, n8x);

  // transpose all three weights into one concatenated (N=4096, K=2048) buffer
  transpose_qkv3<<<dim3(NQKV_ / 32, HID_ / 32), blk, 0, stream>>>(Wq, Wk, Wv, wT);

  // fused QKV GEMM (256^2 pipelined): Q f32 -> d_out, K f32 -> kbuf, V^T bf16 -> vt
  gemm256<1><<<dim3(NQKV_ / QBN, BS / QBM), dim3(512), 0, stream>>>(
      xb, wT, out, kbuf, vt, BS, NQKV_, HID_, S);

  // per-head RMSNorm + RoPE -> bf16 (SCALE folded into Q)
  rmsnorm_rope_o16<<<dim3(BS * H_ / 4),  blk, 0, stream>>>(out,  qb,   qw, cs, sn, H_,  SCALE_);
  rmsnorm_rope_o16<<<dim3(BS * KV_ / 4), blk, 0, stream>>>(kbuf, kb16, kw, cs, sn, KV_, 1.0f);

  // causal MFMA flash attention (KVBLK=128, work-balanced q-tile pairs) -> bf16
  flash_bf16<<<dim3(S / 128, H_, B), blk, 0, stream>>>(qb, kb16, vt, ab16, S, S / 64);

  // Out = abuf @ Wo (f32 into d_out); Wo^T reuses wT
  transpose_bf16<<<dim3(HID_ / 32, (H_ * D_) / 32), blk, 0, stream>>>(Wo, wT, H_ * D_, HID_);
  gemm256<0><<<dim3(HID_ / QBN, BS / QBM), dim3(512), 0, stream>>>(
      ab16, wT, out, nullptr, nullptr, BS, HID_, HID_, S);
}